// Round 12
// baseline (172.654 us; speedup 1.0000x reference)
//
#include <hip/hip_runtime.h>

#define NB   16
#define CIN  256
#define MM   4096
#define COUT 512
#define NH   8
#define DH   64
#define SCALE 0.125f

typedef __attribute__((ext_vector_type(8))) short bf16x8;
typedef __attribute__((ext_vector_type(4))) float f32x4;

// ---- workspace byte offsets ----
#define PEH_OFF   0u         // [256][64] f32
#define PEW_OFF   65536u     // [256][64] f32
#define WQ_OFF    131072u    // [512][256] bf16
#define WKV_OFF   393216u    // [8][128][256] bf16
#define KVP_OFF   917504u    // [128][4][64][64] f32 (fallback path)
#define KSP_OFF   9306112u   // [128][4][64] f32 (fallback path)
#define AEXT_OFF  9437184u   // fallback A_ext; fast path uses region below:
#define KVP6_OFF  9437184u   // [128][6][64][64] f32 = 12.58 MB (ends 22020096)
#define KSP6_OFF  22020096u  // [128][6][64] f32 = 192 KB (ends 22216704)
#define XT_OFF    27787264u  // [16][4096][256] bf16
#define WS_NEED   61341696ull

__device__ __forceinline__ unsigned short f2bf(float f) {
    unsigned int u = __float_as_uint(f);
    u = (u + 0x7FFFu + ((u >> 16) & 1u)) >> 16;
    return (unsigned short)u;
}
__device__ __forceinline__ float phi_elu(float x) {
    return (x >= 0.f ? x + 1.f : __expf(x)) * SCALE;
}
__device__ __forceinline__ void gload_lds16(const void* g, void* l) {
    __builtin_amdgcn_global_load_lds(
        (const __attribute__((address_space(1))) unsigned int*)g,
        (__attribute__((address_space(3))) unsigned int*)l, 16, 0, 0);
}

// ================= FAST PATH =================

// fused prep (PE tables + bf16 weights) + xpose (x -> xT bf16 [b][m][c])
__global__ __launch_bounds__(256) void k_init(const float* __restrict__ x,
                                              const float* __restrict__ Wq,
                                              const float* __restrict__ Wk,
                                              const float* __restrict__ Wv,
                                              char* __restrict__ ws) {
    __shared__ unsigned short tile[64 * 64];
    int blk = blockIdx.x;
    int t = threadIdx.x;
    if (blk < 1664) {
        int idx = blk * 256 + t;
        if (idx < 32768) {
            int which = idx >> 14;
            int r = idx & 16383;
            int c = r >> 6, pos = r & 63;
            float div = __expf(-logf(10000.f) * (float)(c >> 1) * (1.f / 128.f));
            float tt = (float)pos * div;
            float v = (c & 1) ? cosf(tt) : sinf(tt);
            ((float*)(ws + (which ? PEW_OFF : PEH_OFF)))[r] = v;
            return;
        }
        idx -= 32768;
        if (idx < COUT * CIN) {
            ((unsigned short*)(ws + WQ_OFF))[idx] = f2bf(Wq[idx]);
            return;
        }
        idx -= COUT * CIN;
        if (idx < NH * 128 * CIN) {
            int h = idx >> 15;
            int r = idx & 32767;
            int row = r >> 8, c = r & 255;
            float v = (row < 64) ? Wk[(h * 64 + row) * CIN + c]
                                 : Wv[(h * 64 + row - 64) * CIN + c];
            ((unsigned short*)(ws + WKV_OFF))[idx] = f2bf(v);
        }
        return;
    }
    // ---- xpose ----
    int gx = blk - 1664;                 // b*256 + mt*4 + ct
    int ct = gx & 3, mt = (gx >> 2) & 63, b = gx >> 8;
    int m0 = mt * 64, c0 = ct * 64;
    const float* xb = x + ((size_t)b * CIN + c0) * MM + m0;
    int m4 = (t & 15) * 4;
    int cp0 = (t >> 4) * 2;
#pragma unroll
    for (int p = 0; p < 2; ++p) {
        int cp = cp0 + p * 32;
        float4 v0 = *(const float4*)(xb + (size_t)cp * MM + m4);
        float4 v1 = *(const float4*)(xb + (size_t)(cp + 1) * MM + m4);
        float a0[4] = {v0.x, v0.y, v0.z, v0.w};
        float a1[4] = {v1.x, v1.y, v1.z, v1.w};
#pragma unroll
        for (int i = 0; i < 4; ++i) {
            int m = m4 + i;
            unsigned pk = (unsigned)f2bf(a0[i]) | ((unsigned)f2bf(a1[i]) << 16);
            unsigned off = (unsigned)(m * 128) + (((unsigned)(cp * 2)) ^ ((unsigned)(m & 7) << 4));
            *(unsigned*)((char*)tile + off) = pk;
        }
    }
    __syncthreads();
    unsigned short* xt = (unsigned short*)(ws + XT_OFF) + ((size_t)b * MM + m0) * CIN + c0;
#pragma unroll
    for (int p = 0; p < 2; ++p) {
        int id = t + p * 256;
        int m = id >> 3, u = id & 7;
        unsigned off = (unsigned)(m * 128) + (((unsigned)(u ^ (m & 7))) << 4);
        *(bf16x8*)(xt + (size_t)m * CIN + u * 8) = *(const bf16x8*)((const char*)tile + off);
    }
}

// stage 64 rows x 128 cols (half h of a 64x256 xT tile) into a 16KB buffer.
// LDS linear dest; XOR swizzle applied to GLOBAL 16B-unit index (G21).
__device__ __forceinline__ void stage_half(const unsigned short* __restrict__ tile_base, int h,
                                           unsigned short* __restrict__ buf, int l, int w) {
#pragma unroll
    for (int i = 0; i < 4; ++i) {
        int r0 = w * 16 + i * 4;                       // wave-uniform row base
        int m = r0 + (l >> 4);
        unsigned u = (unsigned)(l & 15) ^ (unsigned)(m & 7);
        const char* g = (const char*)tile_base + m * 512 + h * 256 + u * 16;
        gload_lds16(g, (char*)buf + r0 * 256);
    }
}
// read row n, k-elems k..k+7 (k in [0,128), k%8==0)
__device__ __forceinline__ bf16x8 ldsBh(const unsigned short* buf, int n, int k) {
    unsigned off = (unsigned)(n * 256) + (((((unsigned)k) >> 3) ^ ((unsigned)n & 7)) << 4);
    return *(const bf16x8*)((const char*)buf + off);
}

// per (b,h,slice): k,v GEMM from xT + KV/ksum accumulate; dbuf prefetch, 4 waves
// grid 768 = 128 bh x 6 slices (tiles: 11,11,11,11,10,10) -> 3 blocks/CU
__global__ __launch_bounds__(256) void k_kv4(const char* __restrict__ ws) {
    __shared__ unsigned short bufA[64 * 128];  // 16 KB
    __shared__ unsigned short bufB[64 * 128];  // 16 KB
    __shared__ unsigned short kt[64 * 72];     // 9 KB
    __shared__ unsigned short vt[64 * 72];     // 9 KB => 50 KB, 3 blocks/CU
    int t = threadIdx.x, l = t & 63, w = t >> 6;
    int blk = blockIdx.x;
    int wid = (blk & 7) * 96 + (blk >> 3);     // XCD-chunked swizzle (768 = 8*96)
    int s = wid % 6, bh = wid / 6;
    int b = bh >> 3, h = bh & 7;
    int t0 = (s < 4) ? s * 11 : 44 + (s - 4) * 10;
    int nt = (s < 4) ? 11 : 10;
    const unsigned short* xtb = (const unsigned short*)(ws + XT_OFF) + (size_t)b * MM * CIN;
    const unsigned short* wkv = (const unsigned short*)(ws + WKV_OFF) + (size_t)h * 128 * CIN;
    bf16x8 wreg[2][8];
#pragma unroll
    for (int rf = 0; rf < 2; ++rf)
#pragma unroll
        for (int kk = 0; kk < 8; ++kk)
            wreg[rf][kk] = *(const bf16x8*)(wkv + (size_t)(w * 32 + rf * 16 + (l & 15)) * CIN + kk * 32 + (l >> 4) * 8);

    f32x4 kvacc[4] = {};
    float ksum[2][4] = {};

    const unsigned short* base = xtb + (size_t)(t0 * 64) * CIN;
    stage_half(base, 0, bufA, l, w);
    __syncthreads();

    for (int ms = 0; ms < nt; ++ms) {
        const unsigned short* tilep = base + (size_t)(ms * 64) * CIN;
        stage_half(tilep, 1, bufB, l, w);          // prefetch half1

        f32x4 acc[2][4] = {};
#pragma unroll
        for (int kk = 0; kk < 4; ++kk) {           // half0 compute (c 0..127)
            bf16x8 bfr[4];
#pragma unroll
            for (int cf = 0; cf < 4; ++cf)
                bfr[cf] = ldsBh(bufA, cf * 16 + (l & 15), kk * 32 + (l >> 4) * 8);
#pragma unroll
            for (int rf = 0; rf < 2; ++rf)
#pragma unroll
                for (int cf = 0; cf < 4; ++cf)
                    acc[rf][cf] = __builtin_amdgcn_mfma_f32_16x16x32_bf16(wreg[rf][kk], bfr[cf], acc[rf][cf], 0, 0, 0);
        }
        __syncthreads();                            // bufB ready (hidden under half0)

        if (ms < nt - 1)
            stage_half(tilep + 64 * CIN, 0, bufA, l, w);   // prefetch next half0
#pragma unroll
        for (int kk = 0; kk < 4; ++kk) {           // half1 compute (c 128..255)
            bf16x8 bfr[4];
#pragma unroll
            for (int cf = 0; cf < 4; ++cf)
                bfr[cf] = ldsBh(bufB, cf * 16 + (l & 15), kk * 32 + (l >> 4) * 8);
#pragma unroll
            for (int rf = 0; rf < 2; ++rf)
#pragma unroll
                for (int cf = 0; cf < 4; ++cf)
                    acc[rf][cf] = __builtin_amdgcn_mfma_f32_16x16x32_bf16(wreg[rf][4 + kk], bfr[cf], acc[rf][cf], 0, 0, 0);
        }
        // epilogue: waves 0-1 -> phi -> kt ; waves 2-3 -> vt
        if (w < 2) {
#pragma unroll
            for (int rf = 0; rf < 2; ++rf)
#pragma unroll
                for (int cf = 0; cf < 4; ++cf)
#pragma unroll
                    for (int r = 0; r < 4; ++r) {
                        float p = phi_elu(acc[rf][cf][r]);
                        ksum[rf][r] += p;
                        kt[(w * 32 + rf * 16 + ((l >> 4) << 2) + r) * 72 + cf * 16 + (l & 15)] = f2bf(p);
                    }
        } else {
#pragma unroll
            for (int rf = 0; rf < 2; ++rf)
#pragma unroll
                for (int cf = 0; cf < 4; ++cf)
#pragma unroll
                    for (int r = 0; r < 4; ++r)
                        vt[((w - 2) * 32 + rf * 16 + ((l >> 4) << 2) + r) * 72 + cf * 16 + (l & 15)] = f2bf(acc[rf][cf][r]);
        }
        __syncthreads();                            // kt/vt visible; bufA prefetch drained (hidden)
        // KV += phi_k * v^T : wave w -> KV rows w*16..+15, all 64 cols
#pragma unroll
        for (int kk = 0; kk < 2; ++kk) {
            bf16x8 a = *(const bf16x8*)(kt + (w * 16 + (l & 15)) * 72 + kk * 32 + (l >> 4) * 8);
#pragma unroll
            for (int cf = 0; cf < 4; ++cf) {
                bf16x8 bb = *(const bf16x8*)(vt + (cf * 16 + (l & 15)) * 72 + kk * 32 + (l >> 4) * 8);
                kvacc[cf] = __builtin_amdgcn_mfma_f32_16x16x32_bf16(a, bb, kvacc[cf], 0, 0, 0);
            }
        }
        // no trailing barrier: next kt/vt write is after next mid-loop barrier
    }

    float* kvp = (float*)(ws + KVP6_OFF) + ((size_t)(bh * 6 + s)) * 4096;
#pragma unroll
    for (int cf = 0; cf < 4; ++cf)
#pragma unroll
        for (int r = 0; r < 4; ++r) {
            int c = w * 16 + ((l >> 4) << 2) + r;
            kvp[c * 64 + cf * 16 + (l & 15)] = kvacc[cf][r];
        }
    if (w < 2) {
        float* ksp = (float*)(ws + KSP6_OFF) + (bh * 6 + s) * 64;
#pragma unroll
        for (int rf = 0; rf < 2; ++rf)
#pragma unroll
            for (int r = 0; r < 4; ++r) {
                float v = ksum[rf][r];
                v += __shfl_xor(v, 1); v += __shfl_xor(v, 2);
                v += __shfl_xor(v, 4); v += __shfl_xor(v, 8);
                if ((l & 15) == 0)
                    ksp[w * 32 + rf * 16 + ((l >> 4) << 2) + r] = v;
            }
    }
}

// per (b,h,slice): in-block reduce 6 KV partials -> aext, recompute phi(q) from xT,
// out = (A_ext*phi_q)/denom; dbuf prefetch. grid 768 -> 3 blocks/CU
__global__ __launch_bounds__(256) void k_out4(const char* __restrict__ ws, float* __restrict__ out) {
    __shared__ unsigned short bufA[64 * 128];  // 16 KB
    __shared__ unsigned short bufB[64 * 128];  // 16 KB
    __shared__ unsigned short qt[64 * 64];     // 8 KB [m][c] swizzled
    __shared__ unsigned short aext[80 * 72];   // 11.25 KB => 51.25 KB, 3 blocks/CU
    int t = threadIdx.x, l = t & 63, w = t >> 6;
    int blk = blockIdx.x;
    int wid = (blk & 7) * 96 + (blk >> 3);     // XCD-chunked swizzle (768 = 8*96)
    int s = wid % 6, bh = wid / 6;
    int b = bh >> 3, h = bh & 7;
    int t0 = (s < 4) ? s * 11 : 44 + (s - 4) * 10;
    int nt = (s < 4) ? 11 : 10;

    // in-block reduce of the 6 KV/ksum partials -> aext
    {
        const float* kvp = (const float*)(ws + KVP6_OFF) + (size_t)bh * 6 * 4096;
        const float* ksp = (const float*)(ws + KSP6_OFF) + bh * 6 * 64;
        for (int j = t; j < 4096; j += 256) {
            float v = 0.f;
#pragma unroll
            for (int sx = 0; sx < 6; ++sx) v += kvp[sx * 4096 + j];
            aext[(j & 63) * 72 + (j >> 6)] = f2bf(v);   // A_ext[d][c] = KV[c][d]
        }
        if (t < 64) {
            float v = 0.f;
#pragma unroll
            for (int sx = 0; sx < 6; ++sx) v += ksp[sx * 64 + t];
            aext[64 * 72 + t] = f2bf(v);
        }
        for (int j = t; j < 15 * 64; j += 256)
            aext[(65 + (j >> 6)) * 72 + (j & 63)] = 0;
    }

    const unsigned short* xtb = (const unsigned short*)(ws + XT_OFF) + (size_t)b * MM * CIN;
    const unsigned short* wq = (const unsigned short*)(ws + WQ_OFF);
    // wave w: q rows (w>>1)*32 + rf*16, m cols (w&1)*32 + mf*16
    bf16x8 wreg[2][8];
#pragma unroll
    for (int rf = 0; rf < 2; ++rf)
#pragma unroll
        for (int kk = 0; kk < 8; ++kk)
            wreg[rf][kk] = *(const bf16x8*)(wq + (size_t)(h * 64 + (w >> 1) * 32 + rf * 16 + (l & 15)) * CIN + kk * 32 + (l >> 4) * 8);

    const float* pe = (h < 4) ? (const float*)(ws + PEH_OFF) : (const float*)(ws + PEW_OFF);
    int obase = h * 64 - (h < 4 ? 0 : 256);
    float* outbh = out + ((size_t)(b * COUT + h * DH)) * MM;

    const unsigned short* base = xtb + (size_t)(t0 * 64) * CIN;
    stage_half(base, 0, bufA, l, w);
    __syncthreads();                            // also covers aext writes

    for (int ms = 0; ms < nt; ++ms) {
        int m0 = (t0 + ms) * 64;
        const unsigned short* tilep = base + (size_t)(ms * 64) * CIN;
        stage_half(tilep, 1, bufB, l, w);          // prefetch half1

        f32x4 acc[2][2] = {};
#pragma unroll
        for (int kk = 0; kk < 4; ++kk) {           // qGEMM half0
            bf16x8 bfr[2];
#pragma unroll
            for (int mf = 0; mf < 2; ++mf)
                bfr[mf] = ldsBh(bufA, (w & 1) * 32 + mf * 16 + (l & 15), kk * 32 + (l >> 4) * 8);
#pragma unroll
            for (int rf = 0; rf < 2; ++rf)
#pragma unroll
                for (int mf = 0; mf < 2; ++mf)
                    acc[rf][mf] = __builtin_amdgcn_mfma_f32_16x16x32_bf16(wreg[rf][kk], bfr[mf], acc[rf][mf], 0, 0, 0);
        }
        __syncthreads();                            // bufB ready; PV(ms-1) qt-reads separated

        if (ms < nt - 1)
            stage_half(tilep + 64 * CIN, 0, bufA, l, w);   // prefetch next half0
#pragma unroll
        for (int kk = 0; kk < 4; ++kk) {           // qGEMM half1
            bf16x8 bfr[2];
#pragma unroll
            for (int mf = 0; mf < 2; ++mf)
                bfr[mf] = ldsBh(bufB, (w & 1) * 32 + mf * 16 + (l & 15), kk * 32 + (l >> 4) * 8);
#pragma unroll
            for (int rf = 0; rf < 2; ++rf)
#pragma unroll
                for (int mf = 0; mf < 2; ++mf)
                    acc[rf][mf] = __builtin_amdgcn_mfma_f32_16x16x32_bf16(wreg[rf][4 + kk], bfr[mf], acc[rf][mf], 0, 0, 0);
        }
        int im = m0 >> 6;
#pragma unroll
        for (int rf = 0; rf < 2; ++rf) {
#pragma unroll
            for (int mf = 0; mf < 2; ++mf) {
                int mloc = (w & 1) * 32 + mf * 16 + (l & 15);
#pragma unroll
                for (int r = 0; r < 4; ++r) {
                    int c = (w >> 1) * 32 + rf * 16 + ((l >> 4) << 2) + r;
                    int o = obase + c;
                    float pev = (h < 4) ? pe[o * 64 + im] : pe[o * 64 + mloc];
                    float v = phi_elu(acc[rf][mf][r] + pev);
                    unsigned off = (unsigned)(mloc * 128) + (((unsigned)(c * 2)) ^ ((unsigned)(mloc & 7) << 4));
                    *(unsigned short*)((char*)qt + off) = f2bf(v);
                }
            }
        }
        __syncthreads();                            // qt visible; bufA prefetch drained (hidden)

        // PV: wave w owns m-cols w*16..+15
        f32x4 acc2[5] = {};
#pragma unroll
        for (int kk = 0; kk < 2; ++kk) {
            int m = w * 16 + (l & 15);
            unsigned koff = (unsigned)(kk * 64 + (l >> 4) * 16);
            unsigned off = (unsigned)(m * 128) + (koff ^ ((unsigned)(m & 7) << 4));
            bf16x8 bb = *(const bf16x8*)((const char*)qt + off);
#pragma unroll
            for (int rf = 0; rf < 5; ++rf) {
                bf16x8 a = *(const bf16x8*)(aext + (rf * 16 + (l & 15)) * 72 + kk * 32 + (l >> 4) * 8);
                acc2[rf] = __builtin_amdgcn_mfma_f32_16x16x32_bf16(a, bb, acc2[rf], 0, 0, 0);
            }
        }
        float den = __shfl(acc2[4][0], l & 15);
        float inv = 1.f / fmaxf(den, 1e-6f);
        int mcol = m0 + w * 16 + (l & 15);
#pragma unroll
        for (int rf = 0; rf < 4; ++rf)
#pragma unroll
            for (int r = 0; r < 4; ++r)
                outbh[(size_t)(rf * 16 + ((l >> 4) << 2) + r) * MM + mcol] = acc2[rf][r] * inv;
        // no trailing barrier: next qt write is after next mid-loop barrier
    }
}

// ================= OLD (fallback) PATH =================

__global__ void k_prep(const float* __restrict__ Wq, const float* __restrict__ Wk,
                       const float* __restrict__ Wv, char* __restrict__ ws) {
    int idx = blockIdx.x * 256 + threadIdx.x;
    if (idx < 32768) {
        int which = idx >> 14;
        int r = idx & 16383;
        int c = r >> 6, pos = r & 63;
        float div = __expf(-logf(10000.f) * (float)(c >> 1) * (1.f / 128.f));
        float t = (float)pos * div;
        float v = (c & 1) ? cosf(t) : sinf(t);
        ((float*)(ws + (which ? PEW_OFF : PEH_OFF)))[r] = v;
        return;
    }
    idx -= 32768;
    if (idx < COUT * CIN) {
        ((unsigned short*)(ws + WQ_OFF))[idx] = f2bf(Wq[idx]);
        return;
    }
    idx -= COUT * CIN;
    if (idx < NH * 128 * CIN) {
        int h = idx >> 15;
        int r = idx & 32767;
        int row = r >> 8, c = r & 255;
        float v = (row < 64) ? Wk[(h * 64 + row) * CIN + c]
                             : Wv[(h * 64 + row - 64) * CIN + c];
        ((unsigned short*)(ws + WKV_OFF))[idx] = f2bf(v);
    }
}

template<int NTHR>
__device__ __forceinline__ void stage_xT(const float* __restrict__ xb, int m0,
                                         unsigned short* __restrict__ lds, int t) {
    int mg = t & 15;
    for (int c = (t >> 4); c < CIN; c += NTHR / 16) {
        const float* src = xb + c * MM + m0 + mg;
#pragma unroll
        for (int j = 0; j < 4; ++j) {
            int m = mg + 16 * j;
            unsigned off = (unsigned)(m * 512) + (((unsigned)(c * 2)) ^ ((unsigned)(m & 7) << 4));
            *(unsigned short*)((char*)lds + off) = f2bf(src[16 * j]);
        }
    }
}
__device__ __forceinline__ bf16x8 ldsB(const unsigned short* lds, int n, int k) {
    unsigned off = (unsigned)(n * 512) + (((unsigned)(k * 2)) ^ ((unsigned)(n & 7) << 4));
    return *(const bf16x8*)((const char*)lds + off);
}

__global__ __launch_bounds__(512) void k_qgemm(const float* __restrict__ x,
                                               const char* __restrict__ ws,
                                               float* __restrict__ out) {
    __shared__ unsigned short xT[64 * 256];
    int t = threadIdx.x, l = t & 63, w = t >> 6;
    int gx = blockIdx.x;
    int rt = gx & 1;
    int ct = gx >> 1;
    int b = ct >> 6;
    int m0 = (ct & 63) * 64;
    const float* xb = x + (size_t)b * CIN * MM;

    const unsigned short* wq = (const unsigned short*)(ws + WQ_OFF);
    int r0 = rt * 256 + w * 32;
    bf16x8 wreg[2][8];
#pragma unroll
    for (int rf = 0; rf < 2; ++rf)
#pragma unroll
        for (int kk = 0; kk < 8; ++kk)
            wreg[rf][kk] = *(const bf16x8*)(wq + (size_t)(r0 + rf * 16 + (l & 15)) * CIN + kk * 32 + (l >> 4) * 8);

    stage_xT<512>(xb, m0, xT, t);
    __syncthreads();

    f32x4 acc[2][4] = {};
#pragma unroll
    for (int kk = 0; kk < 8; ++kk) {
        bf16x8 bfr[4];
#pragma unroll
        for (int cf = 0; cf < 4; ++cf)
            bfr[cf] = ldsB(xT, cf * 16 + (l & 15), kk * 32 + (l >> 4) * 8);
#pragma unroll
        for (int rf = 0; rf < 2; ++rf)
#pragma unroll
            for (int cf = 0; cf < 4; ++cf)
                acc[rf][cf] = __builtin_amdgcn_mfma_f32_16x16x32_bf16(wreg[rf][kk], bfr[cf], acc[rf][cf], 0, 0, 0);
    }

    const float* peh = (const float*)(ws + PEH_OFF);
    const float* pew = (const float*)(ws + PEW_OFF);
    int im = m0 >> 6;
#pragma unroll
    for (int rf = 0; rf < 2; ++rf) {
#pragma unroll
        for (int cf = 0; cf < 4; ++cf) {
            int mloc = cf * 16 + (l & 15);
#pragma unroll
            for (int r = 0; r < 4; ++r) {
                int o = r0 + rf * 16 + ((l >> 4) << 2) + r;
                float pe = (rt == 0) ? peh[o * 64 + im] : pew[(o - 256) * 64 + mloc];
                float v = phi_elu(acc[rf][cf][r] + pe);
                out[((size_t)(b * COUT + o)) * MM + m0 + mloc] = v;
            }
        }
    }
}

__global__ __launch_bounds__(256) void k_kv(const float* __restrict__ x,
                                            char* __restrict__ ws) {
    __shared__ unsigned short xT[64 * 256];
    __shared__ unsigned short kt[64 * 72];
    __shared__ unsigned short vt[64 * 72];
    int t = threadIdx.x, l = t & 63, w = t >> 6;
    int blk = blockIdx.x;
    int s = blk & 3;
    int bh = blk >> 2;
    int b = bh >> 3, h = bh & 7;
    const float* xb = x + (size_t)b * CIN * MM;

    const unsigned short* wkv = (const unsigned short*)(ws + WKV_OFF) + (size_t)h * 128 * CIN;
    bf16x8 wreg[2][8];
#pragma unroll
    for (int rf = 0; rf < 2; ++rf)
#pragma unroll
        for (int kk = 0; kk < 8; ++kk)
            wreg[rf][kk] = *(const bf16x8*)(wkv + (size_t)(w * 32 + rf * 16 + (l & 15)) * CIN + kk * 32 + (l >> 4) * 8);

    f32x4 kvacc[4] = {};
    float ksum[2][4] = {};

    for (int ms = 0; ms < 16; ++ms) {
        int m0 = s * 1024 + ms * 64;
        if (ms) __syncthreads();
        stage_xT<256>(xb, m0, xT, t);
        __syncthreads();

        f32x4 acc[2][4] = {};
#pragma unroll
        for (int kk = 0; kk < 8; ++kk) {
            bf16x8 bfr[4];
#pragma unroll
            for (int cf = 0; cf < 4; ++cf)
                bfr[cf] = ldsB(xT, cf * 16 + (l & 15), kk * 32 + (l >> 4) * 8);
#pragma unroll
            for (int rf = 0; rf < 2; ++rf)
#pragma unroll
                for (int cf = 0; cf < 4; ++cf)
                    acc[rf][cf] = __builtin_amdgcn_mfma_f32_16x16x32_bf16(wreg[rf][kk], bfr[cf], acc[rf][cf], 0, 0, 0);
        }

        if (w < 2) {
#pragma unroll
            for (int rf = 0; rf < 2; ++rf)
#pragma unroll
                for (int cf = 0; cf < 4; ++cf)
#pragma unroll
                    for (int r = 0; r < 4; ++r) {
                        float p = phi_elu(acc[rf][cf][r]);
                        ksum[rf][r] += p;
                        kt[(w * 32 + rf * 16 + ((l >> 4) << 2) + r) * 72 + cf * 16 + (l & 15)] = f2bf(p);
                    }
        } else {
#pragma unroll
            for (int rf = 0; rf < 2; ++rf)
#pragma unroll
                for (int cf = 0; cf < 4; ++cf)
#pragma unroll
                    for (int r = 0; r < 4; ++r)
                        vt[((w - 2) * 32 + rf * 16 + ((l >> 4) << 2) + r) * 72 + cf * 16 + (l & 15)] = f2bf(acc[rf][cf][r]);
        }
        __syncthreads();

#pragma unroll
        for (int kk = 0; kk < 2; ++kk) {
            bf16x8 a = *(const bf16x8*)(kt + (w * 16 + (l & 15)) * 72 + kk * 32 + (l >> 4) * 8);
#pragma unroll
            for (int cf = 0; cf < 4; ++cf) {
                bf16x8 bb = *(const bf16x8*)(vt + (cf * 16 + (l & 15)) * 72 + kk * 32 + (l >> 4) * 8);
                kvacc[cf] = __builtin_amdgcn_mfma_f32_16x16x32_bf16(a, bb, kvacc[cf], 0, 0, 0);
            }
        }
    }

    float* kvp = (float*)(ws + KVP_OFF) + ((size_t)(bh * 4 + s)) * 4096;
#pragma unroll
    for (int cf = 0; cf < 4; ++cf)
#pragma unroll
        for (int r = 0; r < 4; ++r) {
            int c = w * 16 + ((l >> 4) << 2) + r;
            kvp[c * 64 + cf * 16 + (l & 15)] = kvacc[cf][r];
        }
    if (w < 2) {
        float* ksp = (float*)(ws + KSP_OFF) + (bh * 4 + s) * 64;
#pragma unroll
        for (int rf = 0; rf < 2; ++rf)
#pragma unroll
            for (int r = 0; r < 4; ++r) {
                float v = ksum[rf][r];
                v += __shfl_xor(v, 1); v += __shfl_xor(v, 2);
                v += __shfl_xor(v, 4); v += __shfl_xor(v, 8);
                if ((l & 15) == 0)
                    ksp[w * 32 + rf * 16 + ((l >> 4) << 2) + r] = v;
            }
    }
}

__global__ void k_reduce(char* __restrict__ ws) {
    int bh = blockIdx.x;
    const float* kvp = (const float*)(ws + KVP_OFF) + (size_t)bh * 4 * 4096;
    const float* ksp = (const float*)(ws + KSP_OFF) + bh * 4 * 64;
    unsigned short* a = (unsigned short*)(ws + AEXT_OFF) + (size_t)bh * 80 * 64;
    for (int i = threadIdx.x; i < 80 * 64; i += 256) {
        int d = i >> 6, c = i & 63;
        float v = 0.f;
        if (d < 64) {
#pragma unroll
            for (int s = 0; s < 4; ++s) v += kvp[s * 4096 + c * 64 + d];
        } else if (d == 64) {
#pragma unroll
            for (int s = 0; s < 4; ++s) v += ksp[s * 64 + c];
        }
        a[i] = f2bf(v);
    }
}

__global__ __launch_bounds__(256) void k_out(const char* __restrict__ ws,
                                             float* __restrict__ out) {
    __shared__ unsigned short aext[80 * 72];
    __shared__ unsigned short qt[64 * 72];
    int t = threadIdx.x, l = t & 63, w = t >> 6;
    int blk = blockIdx.x;
    int chunk = blk & 7, bh = blk >> 3;
    int b = bh >> 3, h = bh & 7;

    const unsigned short* asrc = (const unsigned short*)(ws + AEXT_OFF) + (size_t)bh * 80 * 64;
    for (int i = t; i < 80 * 8; i += 256) {
        int row = i >> 3, ch = i & 7;
        *(bf16x8*)(aext + row * 72 + ch * 8) = *(const bf16x8*)(asrc + row * 64 + ch * 8);
    }
    float* outbh = out + ((size_t)(b * COUT + h * DH)) * MM;

    for (int ms = 0; ms < 8; ++ms) {
        int m0 = chunk * 512 + ms * 64;
        __syncthreads();
        {
            int mg = t & 15;
            for (int c = t >> 4; c < 64; c += 16) {
                const float* src = outbh + (size_t)c * MM + m0 + mg;
#pragma unroll
                for (int j = 0; j < 4; ++j)
                    qt[(mg + 16 * j) * 72 + c] = f2bf(src[16 * j]);
            }
        }
        __syncthreads();
        f32x4 acc[5] = {};
#pragma unroll
        for (int kk = 0; kk < 2; ++kk) {
            bf16x8 bb = *(const bf16x8*)(qt + (w * 16 + (l & 15)) * 72 + kk * 32 + (l >> 4) * 8);
#pragma unroll
            for (int rf = 0; rf < 5; ++rf) {
                bf16x8 a = *(const bf16x8*)(aext + (rf * 16 + (l & 15)) * 72 + kk * 32 + (l >> 4) * 8);
                acc[rf] = __builtin_amdgcn_mfma_f32_16x16x32_bf16(a, bb, acc[rf], 0, 0, 0);
            }
        }
        float den = __shfl(acc[4][0], l & 15);
        float inv = 1.f / fmaxf(den, 1e-6f);
        int mcol = m0 + w * 16 + (l & 15);
#pragma unroll
        for (int rf = 0; rf < 4; ++rf)
#pragma unroll
            for (int r = 0; r < 4; ++r)
                outbh[(size_t)(rf * 16 + ((l >> 4) << 2) + r) * MM + mcol] = acc[rf][r] * inv;
    }
}

extern "C" void kernel_launch(void* const* d_in, const int* in_sizes, int n_in,
                              void* d_out, int out_size, void* d_ws, size_t ws_size,
                              hipStream_t stream) {
    const float* x  = (const float*)d_in[0];
    const float* Wq = (const float*)d_in[1];
    const float* Wk = (const float*)d_in[2];
    const float* Wv = (const float*)d_in[3];
    float* out = (float*)d_out;
    char* ws = (char*)d_ws;

    if (ws_size >= WS_NEED) {
        hipLaunchKernelGGL(k_init, dim3(5760), dim3(256), 0, stream, x, Wq, Wk, Wv, ws);
        hipLaunchKernelGGL(k_kv4,  dim3(768),  dim3(256), 0, stream, ws);
        hipLaunchKernelGGL(k_out4, dim3(768),  dim3(256), 0, stream, ws, out);
    } else {
        hipLaunchKernelGGL(k_prep,   dim3(1664), dim3(256), 0, stream, Wq, Wk, Wv, ws);
        hipLaunchKernelGGL(k_qgemm,  dim3(2048), dim3(512), 0, stream, x, ws, out);
        hipLaunchKernelGGL(k_kv,     dim3(512),  dim3(256), 0, stream, x, ws);
        hipLaunchKernelGGL(k_reduce, dim3(128),  dim3(256), 0, stream, ws);
        hipLaunchKernelGGL(k_out,    dim3(1024), dim3(256), 0, stream, ws, out);
    }
}

// Round 13
// 122.991 us; speedup vs baseline: 1.4038x; 1.4038x over previous
//
#include <hip/hip_runtime.h>

#define NB   16
#define CIN  256
#define MM   4096
#define COUT 512
#define NH   8
#define DH   64
#define SCALE 0.125f

typedef __attribute__((ext_vector_type(8))) short bf16x8;
typedef __attribute__((ext_vector_type(4))) float f32x4;

// ---- workspace byte offsets ----
#define PEH_OFF   0u         // [256][64] f32
#define PEW_OFF   65536u     // [256][64] f32
#define WQ_OFF    131072u    // [512][256] bf16
#define WKV_OFF   393216u    // [8][128][256] bf16
#define KVP_OFF   917504u    // [128][4][64][64] f32 KV partials
#define KSP_OFF   9306112u   // [128][4][64] f32 ksum partials
#define AEXT_OFF  9437184u   // [128][80][64] bf16 (fallback path only)
#define XT_OFF    27787264u  // [16][4096][256] bf16
#define WS_NEED   61341696ull

__device__ __forceinline__ unsigned short f2bf(float f) {
    unsigned int u = __float_as_uint(f);
    u = (u + 0x7FFFu + ((u >> 16) & 1u)) >> 16;
    return (unsigned short)u;
}
__device__ __forceinline__ float phi_elu(float x) {
    return (x >= 0.f ? x + 1.f : __expf(x)) * SCALE;
}
__device__ __forceinline__ void gload_lds16(const void* g, void* l) {
    __builtin_amdgcn_global_load_lds(
        (const __attribute__((address_space(1))) unsigned int*)g,
        (__attribute__((address_space(3))) unsigned int*)l, 16, 0, 0);
}

// ================= FAST PATH =================

// fused prep (PE tables + bf16 weights) + xpose (x -> xT bf16 [b][m][c])
// blocks [0,1664): prep ; blocks [1664, 5760): xpose
__global__ __launch_bounds__(256) void k_init(const float* __restrict__ x,
                                              const float* __restrict__ Wq,
                                              const float* __restrict__ Wk,
                                              const float* __restrict__ Wv,
                                              char* __restrict__ ws) {
    __shared__ unsigned short tile[64 * 64];
    int blk = blockIdx.x;
    int t = threadIdx.x;
    if (blk < 1664) {
        int idx = blk * 256 + t;
        if (idx < 32768) {
            int which = idx >> 14;
            int r = idx & 16383;
            int c = r >> 6, pos = r & 63;
            float div = __expf(-logf(10000.f) * (float)(c >> 1) * (1.f / 128.f));
            float tt = (float)pos * div;
            float v = (c & 1) ? cosf(tt) : sinf(tt);
            ((float*)(ws + (which ? PEW_OFF : PEH_OFF)))[r] = v;
            return;
        }
        idx -= 32768;
        if (idx < COUT * CIN) {
            ((unsigned short*)(ws + WQ_OFF))[idx] = f2bf(Wq[idx]);
            return;
        }
        idx -= COUT * CIN;
        if (idx < NH * 128 * CIN) {
            int h = idx >> 15;
            int r = idx & 32767;
            int row = r >> 8, c = r & 255;
            float v = (row < 64) ? Wk[(h * 64 + row) * CIN + c]
                                 : Wv[(h * 64 + row - 64) * CIN + c];
            ((unsigned short*)(ws + WKV_OFF))[idx] = f2bf(v);
        }
        return;
    }
    // ---- xpose ----
    int gx = blk - 1664;                 // b*256 + mt*4 + ct
    int ct = gx & 3, mt = (gx >> 2) & 63, b = gx >> 8;
    int m0 = mt * 64, c0 = ct * 64;
    const float* xb = x + ((size_t)b * CIN + c0) * MM + m0;
    int m4 = (t & 15) * 4;
    int cp0 = (t >> 4) * 2;              // even channel within tile
#pragma unroll
    for (int p = 0; p < 2; ++p) {
        int cp = cp0 + p * 32;
        float4 v0 = *(const float4*)(xb + (size_t)cp * MM + m4);
        float4 v1 = *(const float4*)(xb + (size_t)(cp + 1) * MM + m4);
        float a0[4] = {v0.x, v0.y, v0.z, v0.w};
        float a1[4] = {v1.x, v1.y, v1.z, v1.w};
#pragma unroll
        for (int i = 0; i < 4; ++i) {
            int m = m4 + i;
            unsigned pk = (unsigned)f2bf(a0[i]) | ((unsigned)f2bf(a1[i]) << 16);
            unsigned off = (unsigned)(m * 128) + (((unsigned)(cp * 2)) ^ ((unsigned)(m & 7) << 4));
            *(unsigned*)((char*)tile + off) = pk;
        }
    }
    __syncthreads();
    unsigned short* xt = (unsigned short*)(ws + XT_OFF) + ((size_t)b * MM + m0) * CIN + c0;
#pragma unroll
    for (int p = 0; p < 2; ++p) {
        int id = t + p * 256;
        int m = id >> 3, u = id & 7;
        unsigned off = (unsigned)(m * 128) + (((unsigned)(u ^ (m & 7))) << 4);
        *(bf16x8*)(xt + (size_t)m * CIN + u * 8) = *(const bf16x8*)((const char*)tile + off);
    }
}

// stage 64 rows x 128 cols (half h of a 64x256 xT tile) into a 16KB buffer.
// LDS linear dest; XOR swizzle applied to GLOBAL 16B-unit index (G21).
__device__ __forceinline__ void stage_half(const unsigned short* __restrict__ tile_base, int h,
                                           unsigned short* __restrict__ buf, int l, int w) {
#pragma unroll
    for (int i = 0; i < 4; ++i) {
        int r0 = w * 16 + i * 4;                       // wave-uniform row base
        int m = r0 + (l >> 4);
        unsigned u = (unsigned)(l & 15) ^ (unsigned)(m & 7);
        const char* g = (const char*)tile_base + m * 512 + h * 256 + u * 16;
        gload_lds16(g, (char*)buf + r0 * 256);
    }
}
// read row n, k-elems k..k+7 (k in [0,128), k%8==0)
__device__ __forceinline__ bf16x8 ldsBh(const unsigned short* buf, int n, int k) {
    unsigned off = (unsigned)(n * 256) + (((((unsigned)k) >> 3) ^ ((unsigned)n & 7)) << 4);
    return *(const bf16x8*)((const char*)buf + off);
}

// per (b,h,s): k,v GEMM from xT + KV/ksum accumulate; dbuf prefetch, 4 waves
__global__ __launch_bounds__(256) void k_kv4(const char* __restrict__ ws) {
    __shared__ unsigned short bufA[64 * 128];  // 16 KB
    __shared__ unsigned short bufB[64 * 128];  // 16 KB
    __shared__ unsigned short kt[64 * 72];
    __shared__ unsigned short vt[64 * 72];
    int t = threadIdx.x, l = t & 63, w = t >> 6;
    int blk = blockIdx.x;
    int wid = ((blk & 7) << 6) | (blk >> 3);   // XCD-chunked swizzle (512 = 8*64)
    int s = wid & 3, bh = wid >> 2;
    int b = bh >> 3, h = bh & 7;
    const unsigned short* xtb = (const unsigned short*)(ws + XT_OFF) + (size_t)b * MM * CIN;
    const unsigned short* wkv = (const unsigned short*)(ws + WKV_OFF) + (size_t)h * 128 * CIN;
    bf16x8 wreg[2][8];
#pragma unroll
    for (int rf = 0; rf < 2; ++rf)
#pragma unroll
        for (int kk = 0; kk < 8; ++kk)
            wreg[rf][kk] = *(const bf16x8*)(wkv + (size_t)(w * 32 + rf * 16 + (l & 15)) * CIN + kk * 32 + (l >> 4) * 8);

    f32x4 kvacc[4] = {};
    float ksum[2][4] = {};

    const unsigned short* tile0 = xtb + (size_t)(s * 1024) * CIN;
    stage_half(tile0, 0, bufA, l, w);
    __syncthreads();

    for (int ms = 0; ms < 16; ++ms) {
        const unsigned short* tilep = xtb + (size_t)(s * 1024 + ms * 64) * CIN;
        stage_half(tilep, 1, bufB, l, w);          // prefetch half1

        f32x4 acc[2][4] = {};
#pragma unroll
        for (int kk = 0; kk < 4; ++kk) {           // half0 compute (c 0..127)
            bf16x8 bfr[4];
#pragma unroll
            for (int cf = 0; cf < 4; ++cf)
                bfr[cf] = ldsBh(bufA, cf * 16 + (l & 15), kk * 32 + (l >> 4) * 8);
#pragma unroll
            for (int rf = 0; rf < 2; ++rf)
#pragma unroll
                for (int cf = 0; cf < 4; ++cf)
                    acc[rf][cf] = __builtin_amdgcn_mfma_f32_16x16x32_bf16(wreg[rf][kk], bfr[cf], acc[rf][cf], 0, 0, 0);
        }
        __syncthreads();                            // bufB ready (hidden under half0)

        if (ms < 15)
            stage_half(tilep + 64 * CIN, 0, bufA, l, w);   // prefetch next half0
#pragma unroll
        for (int kk = 0; kk < 4; ++kk) {           // half1 compute (c 128..255)
            bf16x8 bfr[4];
#pragma unroll
            for (int cf = 0; cf < 4; ++cf)
                bfr[cf] = ldsBh(bufB, cf * 16 + (l & 15), kk * 32 + (l >> 4) * 8);
#pragma unroll
            for (int rf = 0; rf < 2; ++rf)
#pragma unroll
                for (int cf = 0; cf < 4; ++cf)
                    acc[rf][cf] = __builtin_amdgcn_mfma_f32_16x16x32_bf16(wreg[rf][4 + kk], bfr[cf], acc[rf][cf], 0, 0, 0);
        }
        // epilogue: waves 0-1 -> phi -> kt ; waves 2-3 -> vt
        if (w < 2) {
#pragma unroll
            for (int rf = 0; rf < 2; ++rf)
#pragma unroll
                for (int cf = 0; cf < 4; ++cf)
#pragma unroll
                    for (int r = 0; r < 4; ++r) {
                        float p = phi_elu(acc[rf][cf][r]);
                        ksum[rf][r] += p;
                        kt[(w * 32 + rf * 16 + ((l >> 4) << 2) + r) * 72 + cf * 16 + (l & 15)] = f2bf(p);
                    }
        } else {
#pragma unroll
            for (int rf = 0; rf < 2; ++rf)
#pragma unroll
                for (int cf = 0; cf < 4; ++cf)
#pragma unroll
                    for (int r = 0; r < 4; ++r)
                        vt[((w - 2) * 32 + rf * 16 + ((l >> 4) << 2) + r) * 72 + cf * 16 + (l & 15)] = f2bf(acc[rf][cf][r]);
        }
        __syncthreads();                            // kt/vt visible; bufA prefetch drained (hidden)
        // KV += phi_k * v^T : wave w -> KV rows w*16..+15, all 64 cols
#pragma unroll
        for (int kk = 0; kk < 2; ++kk) {
            bf16x8 a = *(const bf16x8*)(kt + (w * 16 + (l & 15)) * 72 + kk * 32 + (l >> 4) * 8);
#pragma unroll
            for (int cf = 0; cf < 4; ++cf) {
                bf16x8 bb = *(const bf16x8*)(vt + (cf * 16 + (l & 15)) * 72 + kk * 32 + (l >> 4) * 8);
                kvacc[cf] = __builtin_amdgcn_mfma_f32_16x16x32_bf16(a, bb, kvacc[cf], 0, 0, 0);
            }
        }
        // no trailing barrier: next kt/vt write is after next mid-loop barrier
    }

    float* kvp = (float*)(ws + KVP_OFF) + ((size_t)(bh * 4 + s)) * 4096;
#pragma unroll
    for (int cf = 0; cf < 4; ++cf)
#pragma unroll
        for (int r = 0; r < 4; ++r) {
            int c = w * 16 + ((l >> 4) << 2) + r;
            kvp[c * 64 + cf * 16 + (l & 15)] = kvacc[cf][r];
        }
    if (w < 2) {
        float* ksp = (float*)(ws + KSP_OFF) + (bh * 4 + s) * 64;
#pragma unroll
        for (int rf = 0; rf < 2; ++rf)
#pragma unroll
            for (int r = 0; r < 4; ++r) {
                float v = ksum[rf][r];
                v += __shfl_xor(v, 1); v += __shfl_xor(v, 2);
                v += __shfl_xor(v, 4); v += __shfl_xor(v, 8);
                if ((l & 15) == 0)
                    ksp[w * 32 + rf * 16 + ((l >> 4) << 2) + r] = v;
            }
    }
}

// per (b,h,chunk): in-block reduce KV partials -> aext, recompute phi(q) from xT,
// out = (A_ext*phi_q)/denom; dbuf prefetch
__global__ __launch_bounds__(256) void k_out4(const char* __restrict__ ws, float* __restrict__ out) {
    __shared__ unsigned short bufA[64 * 128];  // 16 KB
    __shared__ unsigned short bufB[64 * 128];  // 16 KB
    __shared__ unsigned short qt[64 * 64];     // [m][c] swizzled, 8 KB
    __shared__ unsigned short aext[80 * 72];   // 11.25 KB
    int t = threadIdx.x, l = t & 63, w = t >> 6;
    int blk = blockIdx.x;
    int wid = ((blk & 7) << 6) | (blk >> 3);   // XCD-chunked swizzle (512 = 8*64)
    int chunk = wid & 3, bh = wid >> 2;
    int b = bh >> 3, h = bh & 7;

    // in-block reduce of the 4 KV/ksum partials -> aext (replaces k_reduce)
    {
        const float* kvp = (const float*)(ws + KVP_OFF) + (size_t)bh * 4 * 4096;
        const float* ksp = (const float*)(ws + KSP_OFF) + bh * 4 * 64;
        for (int j = t; j < 4096; j += 256) {
            float v = kvp[j] + kvp[4096 + j] + kvp[8192 + j] + kvp[12288 + j];
            aext[(j & 63) * 72 + (j >> 6)] = f2bf(v);   // A_ext[d][c] = KV[c][d]
        }
        if (t < 64) {
            float v = ksp[t] + ksp[64 + t] + ksp[128 + t] + ksp[192 + t];
            aext[64 * 72 + t] = f2bf(v);
        }
        for (int j = t; j < 15 * 64; j += 256)
            aext[(65 + (j >> 6)) * 72 + (j & 63)] = 0;
    }

    const unsigned short* xtb = (const unsigned short*)(ws + XT_OFF) + (size_t)b * MM * CIN;
    const unsigned short* wq = (const unsigned short*)(ws + WQ_OFF);
    // wave w: q rows (w>>1)*32 + rf*16, m cols (w&1)*32 + mf*16
    bf16x8 wreg[2][8];
#pragma unroll
    for (int rf = 0; rf < 2; ++rf)
#pragma unroll
        for (int kk = 0; kk < 8; ++kk)
            wreg[rf][kk] = *(const bf16x8*)(wq + (size_t)(h * 64 + (w >> 1) * 32 + rf * 16 + (l & 15)) * CIN + kk * 32 + (l >> 4) * 8);

    const float* pe = (h < 4) ? (const float*)(ws + PEH_OFF) : (const float*)(ws + PEW_OFF);
    int obase = h * 64 - (h < 4 ? 0 : 256);
    float* outbh = out + ((size_t)(b * COUT + h * DH)) * MM;

    const unsigned short* tile0 = xtb + (size_t)(chunk * 1024) * CIN;
    stage_half(tile0, 0, bufA, l, w);
    __syncthreads();                            // also covers aext writes

    for (int ms = 0; ms < 16; ++ms) {
        int m0 = chunk * 1024 + ms * 64;
        const unsigned short* tilep = xtb + (size_t)m0 * CIN;
        stage_half(tilep, 1, bufB, l, w);          // prefetch half1

        f32x4 acc[2][2] = {};
#pragma unroll
        for (int kk = 0; kk < 4; ++kk) {           // qGEMM half0
            bf16x8 bfr[2];
#pragma unroll
            for (int mf = 0; mf < 2; ++mf)
                bfr[mf] = ldsBh(bufA, (w & 1) * 32 + mf * 16 + (l & 15), kk * 32 + (l >> 4) * 8);
#pragma unroll
            for (int rf = 0; rf < 2; ++rf)
#pragma unroll
                for (int mf = 0; mf < 2; ++mf)
                    acc[rf][mf] = __builtin_amdgcn_mfma_f32_16x16x32_bf16(wreg[rf][kk], bfr[mf], acc[rf][mf], 0, 0, 0);
        }
        __syncthreads();                            // bufB ready; PV(ms-1) qt-reads separated

        if (ms < 15)
            stage_half(tilep + 64 * CIN, 0, bufA, l, w);   // prefetch next half0
#pragma unroll
        for (int kk = 0; kk < 4; ++kk) {           // qGEMM half1
            bf16x8 bfr[2];
#pragma unroll
            for (int mf = 0; mf < 2; ++mf)
                bfr[mf] = ldsBh(bufB, (w & 1) * 32 + mf * 16 + (l & 15), kk * 32 + (l >> 4) * 8);
#pragma unroll
            for (int rf = 0; rf < 2; ++rf)
#pragma unroll
                for (int mf = 0; mf < 2; ++mf)
                    acc[rf][mf] = __builtin_amdgcn_mfma_f32_16x16x32_bf16(wreg[rf][4 + kk], bfr[mf], acc[rf][mf], 0, 0, 0);
        }
        int im = m0 >> 6;
#pragma unroll
        for (int rf = 0; rf < 2; ++rf) {
#pragma unroll
            for (int mf = 0; mf < 2; ++mf) {
                int mloc = (w & 1) * 32 + mf * 16 + (l & 15);
#pragma unroll
                for (int r = 0; r < 4; ++r) {
                    int c = (w >> 1) * 32 + rf * 16 + ((l >> 4) << 2) + r;
                    int o = obase + c;
                    float pev = (h < 4) ? pe[o * 64 + im] : pe[o * 64 + mloc];
                    float v = phi_elu(acc[rf][mf][r] + pev);
                    unsigned off = (unsigned)(mloc * 128) + (((unsigned)(c * 2)) ^ ((unsigned)(mloc & 7) << 4));
                    *(unsigned short*)((char*)qt + off) = f2bf(v);
                }
            }
        }
        __syncthreads();                            // qt visible; bufA prefetch drained (hidden)

        // PV: wave w owns m-cols w*16..+15
        f32x4 acc2[5] = {};
#pragma unroll
        for (int kk = 0; kk < 2; ++kk) {
            int m = w * 16 + (l & 15);
            unsigned koff = (unsigned)(kk * 64 + (l >> 4) * 16);
            unsigned off = (unsigned)(m * 128) + (koff ^ ((unsigned)(m & 7) << 4));
            bf16x8 bb = *(const bf16x8*)((const char*)qt + off);
#pragma unroll
            for (int rf = 0; rf < 5; ++rf) {
                bf16x8 a = *(const bf16x8*)(aext + (rf * 16 + (l & 15)) * 72 + kk * 32 + (l >> 4) * 8);
                acc2[rf] = __builtin_amdgcn_mfma_f32_16x16x32_bf16(a, bb, acc2[rf], 0, 0, 0);
            }
        }
        float den = __shfl(acc2[4][0], l & 15);
        float inv = 1.f / fmaxf(den, 1e-6f);
        int mcol = m0 + w * 16 + (l & 15);
#pragma unroll
        for (int rf = 0; rf < 4; ++rf)
#pragma unroll
            for (int r = 0; r < 4; ++r)
                outbh[(size_t)(rf * 16 + ((l >> 4) << 2) + r) * MM + mcol] = acc2[rf][r] * inv;
        // no trailing barrier: next qt write is after next mid-loop barrier
    }
}

// ================= OLD (fallback) PATH =================

__global__ void k_prep(const float* __restrict__ Wq, const float* __restrict__ Wk,
                       const float* __restrict__ Wv, char* __restrict__ ws) {
    int idx = blockIdx.x * 256 + threadIdx.x;
    if (idx < 32768) {
        int which = idx >> 14;
        int r = idx & 16383;
        int c = r >> 6, pos = r & 63;
        float div = __expf(-logf(10000.f) * (float)(c >> 1) * (1.f / 128.f));
        float t = (float)pos * div;
        float v = (c & 1) ? cosf(t) : sinf(t);
        ((float*)(ws + (which ? PEW_OFF : PEH_OFF)))[r] = v;
        return;
    }
    idx -= 32768;
    if (idx < COUT * CIN) {
        ((unsigned short*)(ws + WQ_OFF))[idx] = f2bf(Wq[idx]);
        return;
    }
    idx -= COUT * CIN;
    if (idx < NH * 128 * CIN) {
        int h = idx >> 15;
        int r = idx & 32767;
        int row = r >> 8, c = r & 255;
        float v = (row < 64) ? Wk[(h * 64 + row) * CIN + c]
                             : Wv[(h * 64 + row - 64) * CIN + c];
        ((unsigned short*)(ws + WKV_OFF))[idx] = f2bf(v);
    }
}

template<int NTHR>
__device__ __forceinline__ void stage_xT(const float* __restrict__ xb, int m0,
                                         unsigned short* __restrict__ lds, int t) {
    int mg = t & 15;
    for (int c = (t >> 4); c < CIN; c += NTHR / 16) {
        const float* src = xb + c * MM + m0 + mg;
#pragma unroll
        for (int j = 0; j < 4; ++j) {
            int m = mg + 16 * j;
            unsigned off = (unsigned)(m * 512) + (((unsigned)(c * 2)) ^ ((unsigned)(m & 7) << 4));
            *(unsigned short*)((char*)lds + off) = f2bf(src[16 * j]);
        }
    }
}
__device__ __forceinline__ bf16x8 ldsB(const unsigned short* lds, int n, int k) {
    unsigned off = (unsigned)(n * 512) + (((unsigned)(k * 2)) ^ ((unsigned)(n & 7) << 4));
    return *(const bf16x8*)((const char*)lds + off);
}

__global__ __launch_bounds__(512) void k_qgemm(const float* __restrict__ x,
                                               const char* __restrict__ ws,
                                               float* __restrict__ out) {
    __shared__ unsigned short xT[64 * 256];
    int t = threadIdx.x, l = t & 63, w = t >> 6;
    int gx = blockIdx.x;
    int rt = gx & 1;
    int ct = gx >> 1;
    int b = ct >> 6;
    int m0 = (ct & 63) * 64;
    const float* xb = x + (size_t)b * CIN * MM;

    const unsigned short* wq = (const unsigned short*)(ws + WQ_OFF);
    int r0 = rt * 256 + w * 32;
    bf16x8 wreg[2][8];
#pragma unroll
    for (int rf = 0; rf < 2; ++rf)
#pragma unroll
        for (int kk = 0; kk < 8; ++kk)
            wreg[rf][kk] = *(const bf16x8*)(wq + (size_t)(r0 + rf * 16 + (l & 15)) * CIN + kk * 32 + (l >> 4) * 8);

    stage_xT<512>(xb, m0, xT, t);
    __syncthreads();

    f32x4 acc[2][4] = {};
#pragma unroll
    for (int kk = 0; kk < 8; ++kk) {
        bf16x8 bfr[4];
#pragma unroll
        for (int cf = 0; cf < 4; ++cf)
            bfr[cf] = ldsB(xT, cf * 16 + (l & 15), kk * 32 + (l >> 4) * 8);
#pragma unroll
        for (int rf = 0; rf < 2; ++rf)
#pragma unroll
            for (int cf = 0; cf < 4; ++cf)
                acc[rf][cf] = __builtin_amdgcn_mfma_f32_16x16x32_bf16(wreg[rf][kk], bfr[cf], acc[rf][cf], 0, 0, 0);
    }

    const float* peh = (const float*)(ws + PEH_OFF);
    const float* pew = (const float*)(ws + PEW_OFF);
    int im = m0 >> 6;
#pragma unroll
    for (int rf = 0; rf < 2; ++rf) {
#pragma unroll
        for (int cf = 0; cf < 4; ++cf) {
            int mloc = cf * 16 + (l & 15);
#pragma unroll
            for (int r = 0; r < 4; ++r) {
                int o = r0 + rf * 16 + ((l >> 4) << 2) + r;
                float pe = (rt == 0) ? peh[o * 64 + im] : pew[(o - 256) * 64 + mloc];
                float v = phi_elu(acc[rf][cf][r] + pe);
                out[((size_t)(b * COUT + o)) * MM + m0 + mloc] = v;
            }
        }
    }
}

__global__ __launch_bounds__(256) void k_kv(const float* __restrict__ x,
                                            char* __restrict__ ws) {
    __shared__ unsigned short xT[64 * 256];
    __shared__ unsigned short kt[64 * 72];
    __shared__ unsigned short vt[64 * 72];
    int t = threadIdx.x, l = t & 63, w = t >> 6;
    int blk = blockIdx.x;
    int s = blk & 3;
    int bh = blk >> 2;
    int b = bh >> 3, h = bh & 7;
    const float* xb = x + (size_t)b * CIN * MM;

    const unsigned short* wkv = (const unsigned short*)(ws + WKV_OFF) + (size_t)h * 128 * CIN;
    bf16x8 wreg[2][8];
#pragma unroll
    for (int rf = 0; rf < 2; ++rf)
#pragma unroll
        for (int kk = 0; kk < 8; ++kk)
            wreg[rf][kk] = *(const bf16x8*)(wkv + (size_t)(w * 32 + rf * 16 + (l & 15)) * CIN + kk * 32 + (l >> 4) * 8);

    f32x4 kvacc[4] = {};
    float ksum[2][4] = {};

    for (int ms = 0; ms < 16; ++ms) {
        int m0 = s * 1024 + ms * 64;
        if (ms) __syncthreads();
        stage_xT<256>(xb, m0, xT, t);
        __syncthreads();

        f32x4 acc[2][4] = {};
#pragma unroll
        for (int kk = 0; kk < 8; ++kk) {
            bf16x8 bfr[4];
#pragma unroll
            for (int cf = 0; cf < 4; ++cf)
                bfr[cf] = ldsB(xT, cf * 16 + (l & 15), kk * 32 + (l >> 4) * 8);
#pragma unroll
            for (int rf = 0; rf < 2; ++rf)
#pragma unroll
                for (int cf = 0; cf < 4; ++cf)
                    acc[rf][cf] = __builtin_amdgcn_mfma_f32_16x16x32_bf16(wreg[rf][kk], bfr[cf], acc[rf][cf], 0, 0, 0);
        }

        if (w < 2) {
#pragma unroll
            for (int rf = 0; rf < 2; ++rf)
#pragma unroll
                for (int cf = 0; cf < 4; ++cf)
#pragma unroll
                    for (int r = 0; r < 4; ++r) {
                        float p = phi_elu(acc[rf][cf][r]);
                        ksum[rf][r] += p;
                        kt[(w * 32 + rf * 16 + ((l >> 4) << 2) + r) * 72 + cf * 16 + (l & 15)] = f2bf(p);
                    }
        } else {
#pragma unroll
            for (int rf = 0; rf < 2; ++rf)
#pragma unroll
                for (int cf = 0; cf < 4; ++cf)
#pragma unroll
                    for (int r = 0; r < 4; ++r)
                        vt[((w - 2) * 32 + rf * 16 + ((l >> 4) << 2) + r) * 72 + cf * 16 + (l & 15)] = f2bf(acc[rf][cf][r]);
        }
        __syncthreads();

#pragma unroll
        for (int kk = 0; kk < 2; ++kk) {
            bf16x8 a = *(const bf16x8*)(kt + (w * 16 + (l & 15)) * 72 + kk * 32 + (l >> 4) * 8);
#pragma unroll
            for (int cf = 0; cf < 4; ++cf) {
                bf16x8 bb = *(const bf16x8*)(vt + (cf * 16 + (l & 15)) * 72 + kk * 32 + (l >> 4) * 8);
                kvacc[cf] = __builtin_amdgcn_mfma_f32_16x16x32_bf16(a, bb, kvacc[cf], 0, 0, 0);
            }
        }
    }

    float* kvp = (float*)(ws + KVP_OFF) + ((size_t)(bh * 4 + s)) * 4096;
#pragma unroll
    for (int cf = 0; cf < 4; ++cf)
#pragma unroll
        for (int r = 0; r < 4; ++r) {
            int c = w * 16 + ((l >> 4) << 2) + r;
            kvp[c * 64 + cf * 16 + (l & 15)] = kvacc[cf][r];
        }
    if (w < 2) {
        float* ksp = (float*)(ws + KSP_OFF) + (bh * 4 + s) * 64;
#pragma unroll
        for (int rf = 0; rf < 2; ++rf)
#pragma unroll
            for (int r = 0; r < 4; ++r) {
                float v = ksum[rf][r];
                v += __shfl_xor(v, 1); v += __shfl_xor(v, 2);
                v += __shfl_xor(v, 4); v += __shfl_xor(v, 8);
                if ((l & 15) == 0)
                    ksp[w * 32 + rf * 16 + ((l >> 4) << 2) + r] = v;
            }
    }
}

__global__ void k_reduce(char* __restrict__ ws) {
    int bh = blockIdx.x;
    const float* kvp = (const float*)(ws + KVP_OFF) + (size_t)bh * 4 * 4096;
    const float* ksp = (const float*)(ws + KSP_OFF) + bh * 4 * 64;
    unsigned short* a = (unsigned short*)(ws + AEXT_OFF) + (size_t)bh * 80 * 64;
    for (int i = threadIdx.x; i < 80 * 64; i += 256) {
        int d = i >> 6, c = i & 63;
        float v = 0.f;
        if (d < 64) {
#pragma unroll
            for (int s = 0; s < 4; ++s) v += kvp[s * 4096 + c * 64 + d];
        } else if (d == 64) {
#pragma unroll
            for (int s = 0; s < 4; ++s) v += ksp[s * 64 + c];
        }
        a[i] = f2bf(v);
    }
}

__global__ __launch_bounds__(256) void k_out(const char* __restrict__ ws,
                                             float* __restrict__ out) {
    __shared__ unsigned short aext[80 * 72];
    __shared__ unsigned short qt[64 * 72];
    int t = threadIdx.x, l = t & 63, w = t >> 6;
    int blk = blockIdx.x;
    int chunk = blk & 7, bh = blk >> 3;
    int b = bh >> 3, h = bh & 7;

    const unsigned short* asrc = (const unsigned short*)(ws + AEXT_OFF) + (size_t)bh * 80 * 64;
    for (int i = t; i < 80 * 8; i += 256) {
        int row = i >> 3, ch = i & 7;
        *(bf16x8*)(aext + row * 72 + ch * 8) = *(const bf16x8*)(asrc + row * 64 + ch * 8);
    }
    float* outbh = out + ((size_t)(b * COUT + h * DH)) * MM;

    for (int ms = 0; ms < 8; ++ms) {
        int m0 = chunk * 512 + ms * 64;
        __syncthreads();
        {
            int mg = t & 15;
            for (int c = t >> 4; c < 64; c += 16) {
                const float* src = outbh + (size_t)c * MM + m0 + mg;
#pragma unroll
                for (int j = 0; j < 4; ++j)
                    qt[(mg + 16 * j) * 72 + c] = f2bf(src[16 * j]);
            }
        }
        __syncthreads();
        f32x4 acc[5] = {};
#pragma unroll
        for (int kk = 0; kk < 2; ++kk) {
            bf16x8 bb = *(const bf16x8*)(qt + (w * 16 + (l & 15)) * 72 + kk * 32 + (l >> 4) * 8);
#pragma unroll
            for (int rf = 0; rf < 5; ++rf) {
                bf16x8 a = *(const bf16x8*)(aext + (rf * 16 + (l & 15)) * 72 + kk * 32 + (l >> 4) * 8);
                acc[rf] = __builtin_amdgcn_mfma_f32_16x16x32_bf16(a, bb, acc[rf], 0, 0, 0);
            }
        }
        float den = __shfl(acc[4][0], l & 15);
        float inv = 1.f / fmaxf(den, 1e-6f);
        int mcol = m0 + w * 16 + (l & 15);
#pragma unroll
        for (int rf = 0; rf < 4; ++rf)
#pragma unroll
            for (int r = 0; r < 4; ++r)
                outbh[(size_t)(rf * 16 + ((l >> 4) << 2) + r) * MM + mcol] = acc[rf][r] * inv;
    }
}

extern "C" void kernel_launch(void* const* d_in, const int* in_sizes, int n_in,
                              void* d_out, int out_size, void* d_ws, size_t ws_size,
                              hipStream_t stream) {
    const float* x  = (const float*)d_in[0];
    const float* Wq = (const float*)d_in[1];
    const float* Wk = (const float*)d_in[2];
    const float* Wv = (const float*)d_in[3];
    float* out = (float*)d_out;
    char* ws = (char*)d_ws;

    if (ws_size >= WS_NEED) {
        hipLaunchKernelGGL(k_init, dim3(5760), dim3(256), 0, stream, x, Wq, Wk, Wv, ws);
        hipLaunchKernelGGL(k_kv4,  dim3(512),  dim3(256), 0, stream, ws);
        hipLaunchKernelGGL(k_out4, dim3(512),  dim3(256), 0, stream, ws, out);
    } else {
        hipLaunchKernelGGL(k_prep,   dim3(1664), dim3(256), 0, stream, Wq, Wk, Wv, ws);
        hipLaunchKernelGGL(k_qgemm,  dim3(2048), dim3(512), 0, stream, x, ws, out);
        hipLaunchKernelGGL(k_kv,     dim3(512),  dim3(256), 0, stream, x, ws);
        hipLaunchKernelGGL(k_reduce, dim3(128),  dim3(256), 0, stream, ws);
        hipLaunchKernelGGL(k_out,    dim3(1024), dim3(256), 0, stream, ws, out);
    }
}

// Round 14
// 122.584 us; speedup vs baseline: 1.4085x; 1.0033x over previous
//
#include <hip/hip_runtime.h>

#define NB   16
#define CIN  256
#define MM   4096
#define COUT 512
#define NH   8
#define DH   64
#define SCALE 0.125f

typedef __attribute__((ext_vector_type(8))) short bf16x8;
typedef __attribute__((ext_vector_type(4))) float f32x4;

// ---- workspace byte offsets ----
#define PEH_OFF   0u         // [256][64] f32
#define PEW_OFF   65536u     // [256][64] f32
#define WQ_OFF    131072u    // [512][256] bf16
#define WKV_OFF   393216u    // [8][128][256] bf16
#define KVP_OFF   917504u    // [128][4][64][64] f32 KV partials
#define KSP_OFF   9306112u   // [128][4][64] f32 ksum partials
#define AEXT_OFF  9437184u   // [128][80][64] bf16 (fallback path only)
#define XT_OFF    27787264u  // [16][4096][256] bf16
#define WS_NEED   61341696ull

__device__ __forceinline__ unsigned short f2bf(float f) {
    unsigned int u = __float_as_uint(f);
    u = (u + 0x7FFFu + ((u >> 16) & 1u)) >> 16;
    return (unsigned short)u;
}
__device__ __forceinline__ float phi_elu(float x) {
    return (x >= 0.f ? x + 1.f : __expf(x)) * SCALE;
}
__device__ __forceinline__ void gload_lds16(const void* g, void* l) {
    __builtin_amdgcn_global_load_lds(
        (const __attribute__((address_space(1))) unsigned int*)g,
        (__attribute__((address_space(3))) unsigned int*)l, 16, 0, 0);
}

// ================= FAST PATH =================

// fused prep (PE tables + bf16 weights) + xpose (x -> xT bf16 [b][m][c])
// blocks [0,1664): prep ; blocks [1664, 5760): xpose
__global__ __launch_bounds__(256) void k_init(const float* __restrict__ x,
                                              const float* __restrict__ Wq,
                                              const float* __restrict__ Wk,
                                              const float* __restrict__ Wv,
                                              char* __restrict__ ws) {
    __shared__ unsigned short tile[64 * 64];
    int blk = blockIdx.x;
    int t = threadIdx.x;
    if (blk < 1664) {
        int idx = blk * 256 + t;
        if (idx < 32768) {
            int which = idx >> 14;
            int r = idx & 16383;
            int c = r >> 6, pos = r & 63;
            float div = __expf(-logf(10000.f) * (float)(c >> 1) * (1.f / 128.f));
            float tt = (float)pos * div;
            float v = (c & 1) ? cosf(tt) : sinf(tt);
            ((float*)(ws + (which ? PEW_OFF : PEH_OFF)))[r] = v;
            return;
        }
        idx -= 32768;
        if (idx < COUT * CIN) {
            ((unsigned short*)(ws + WQ_OFF))[idx] = f2bf(Wq[idx]);
            return;
        }
        idx -= COUT * CIN;
        if (idx < NH * 128 * CIN) {
            int h = idx >> 15;
            int r = idx & 32767;
            int row = r >> 8, c = r & 255;
            float v = (row < 64) ? Wk[(h * 64 + row) * CIN + c]
                                 : Wv[(h * 64 + row - 64) * CIN + c];
            ((unsigned short*)(ws + WKV_OFF))[idx] = f2bf(v);
        }
        return;
    }
    // ---- xpose ----
    int gx = blk - 1664;                 // b*256 + mt*4 + ct
    int ct = gx & 3, mt = (gx >> 2) & 63, b = gx >> 8;
    int m0 = mt * 64, c0 = ct * 64;
    const float* xb = x + ((size_t)b * CIN + c0) * MM + m0;
    int m4 = (t & 15) * 4;
    int cp0 = (t >> 4) * 2;              // even channel within tile
#pragma unroll
    for (int p = 0; p < 2; ++p) {
        int cp = cp0 + p * 32;
        float4 v0 = *(const float4*)(xb + (size_t)cp * MM + m4);
        float4 v1 = *(const float4*)(xb + (size_t)(cp + 1) * MM + m4);
        float a0[4] = {v0.x, v0.y, v0.z, v0.w};
        float a1[4] = {v1.x, v1.y, v1.z, v1.w};
#pragma unroll
        for (int i = 0; i < 4; ++i) {
            int m = m4 + i;
            unsigned pk = (unsigned)f2bf(a0[i]) | ((unsigned)f2bf(a1[i]) << 16);
            unsigned off = (unsigned)(m * 128) + (((unsigned)(cp * 2)) ^ ((unsigned)(m & 7) << 4));
            *(unsigned*)((char*)tile + off) = pk;
        }
    }
    __syncthreads();
    unsigned short* xt = (unsigned short*)(ws + XT_OFF) + ((size_t)b * MM + m0) * CIN + c0;
#pragma unroll
    for (int p = 0; p < 2; ++p) {
        int id = t + p * 256;
        int m = id >> 3, u = id & 7;
        unsigned off = (unsigned)(m * 128) + (((unsigned)(u ^ (m & 7))) << 4);
        *(bf16x8*)(xt + (size_t)m * CIN + u * 8) = *(const bf16x8*)((const char*)tile + off);
    }
}

// stage 64 rows x 128 cols (half h of a 64x256 xT tile) into a 16KB buffer.
// LDS linear dest; XOR swizzle applied to GLOBAL 16B-unit index (G21).
__device__ __forceinline__ void stage_half(const unsigned short* __restrict__ tile_base, int h,
                                           unsigned short* __restrict__ buf, int l, int w) {
#pragma unroll
    for (int i = 0; i < 4; ++i) {
        int r0 = w * 16 + i * 4;                       // wave-uniform row base
        int m = r0 + (l >> 4);
        unsigned u = (unsigned)(l & 15) ^ (unsigned)(m & 7);
        const char* g = (const char*)tile_base + m * 512 + h * 256 + u * 16;
        gload_lds16(g, (char*)buf + r0 * 256);
    }
}
// read row n, k-elems k..k+7 (k in [0,128), k%8==0)
__device__ __forceinline__ bf16x8 ldsBh(const unsigned short* buf, int n, int k) {
    unsigned off = (unsigned)(n * 256) + (((((unsigned)k) >> 3) ^ ((unsigned)n & 7)) << 4);
    return *(const bf16x8*)((const char*)buf + off);
}

// per (b,h,s): k,v GEMM from xT + KV/ksum accumulate; dbuf prefetch, 4 waves
// T5: s_setprio(1) around MFMA clusters (cross-block phase diversity on CU)
__global__ __launch_bounds__(256) void k_kv4(const char* __restrict__ ws) {
    __shared__ unsigned short bufA[64 * 128];  // 16 KB
    __shared__ unsigned short bufB[64 * 128];  // 16 KB
    __shared__ unsigned short kt[64 * 72];
    __shared__ unsigned short vt[64 * 72];
    int t = threadIdx.x, l = t & 63, w = t >> 6;
    int blk = blockIdx.x;
    int wid = ((blk & 7) << 6) | (blk >> 3);   // XCD-chunked swizzle (512 = 8*64)
    int s = wid & 3, bh = wid >> 2;
    int b = bh >> 3, h = bh & 7;
    const unsigned short* xtb = (const unsigned short*)(ws + XT_OFF) + (size_t)b * MM * CIN;
    const unsigned short* wkv = (const unsigned short*)(ws + WKV_OFF) + (size_t)h * 128 * CIN;
    bf16x8 wreg[2][8];
#pragma unroll
    for (int rf = 0; rf < 2; ++rf)
#pragma unroll
        for (int kk = 0; kk < 8; ++kk)
            wreg[rf][kk] = *(const bf16x8*)(wkv + (size_t)(w * 32 + rf * 16 + (l & 15)) * CIN + kk * 32 + (l >> 4) * 8);

    f32x4 kvacc[4] = {};
    float ksum[2][4] = {};

    const unsigned short* tile0 = xtb + (size_t)(s * 1024) * CIN;
    stage_half(tile0, 0, bufA, l, w);
    __syncthreads();

    for (int ms = 0; ms < 16; ++ms) {
        const unsigned short* tilep = xtb + (size_t)(s * 1024 + ms * 64) * CIN;
        stage_half(tilep, 1, bufB, l, w);          // prefetch half1

        f32x4 acc[2][4] = {};
        __builtin_amdgcn_s_setprio(1);
#pragma unroll
        for (int kk = 0; kk < 4; ++kk) {           // half0 compute (c 0..127)
            bf16x8 bfr[4];
#pragma unroll
            for (int cf = 0; cf < 4; ++cf)
                bfr[cf] = ldsBh(bufA, cf * 16 + (l & 15), kk * 32 + (l >> 4) * 8);
#pragma unroll
            for (int rf = 0; rf < 2; ++rf)
#pragma unroll
                for (int cf = 0; cf < 4; ++cf)
                    acc[rf][cf] = __builtin_amdgcn_mfma_f32_16x16x32_bf16(wreg[rf][kk], bfr[cf], acc[rf][cf], 0, 0, 0);
        }
        __builtin_amdgcn_s_setprio(0);
        __syncthreads();                            // bufB ready (hidden under half0)

        if (ms < 15)
            stage_half(tilep + 64 * CIN, 0, bufA, l, w);   // prefetch next half0
        __builtin_amdgcn_s_setprio(1);
#pragma unroll
        for (int kk = 0; kk < 4; ++kk) {           // half1 compute (c 128..255)
            bf16x8 bfr[4];
#pragma unroll
            for (int cf = 0; cf < 4; ++cf)
                bfr[cf] = ldsBh(bufB, cf * 16 + (l & 15), kk * 32 + (l >> 4) * 8);
#pragma unroll
            for (int rf = 0; rf < 2; ++rf)
#pragma unroll
                for (int cf = 0; cf < 4; ++cf)
                    acc[rf][cf] = __builtin_amdgcn_mfma_f32_16x16x32_bf16(wreg[rf][4 + kk], bfr[cf], acc[rf][cf], 0, 0, 0);
        }
        __builtin_amdgcn_s_setprio(0);
        // epilogue: waves 0-1 -> phi -> kt ; waves 2-3 -> vt
        if (w < 2) {
#pragma unroll
            for (int rf = 0; rf < 2; ++rf)
#pragma unroll
                for (int cf = 0; cf < 4; ++cf)
#pragma unroll
                    for (int r = 0; r < 4; ++r) {
                        float p = phi_elu(acc[rf][cf][r]);
                        ksum[rf][r] += p;
                        kt[(w * 32 + rf * 16 + ((l >> 4) << 2) + r) * 72 + cf * 16 + (l & 15)] = f2bf(p);
                    }
        } else {
#pragma unroll
            for (int rf = 0; rf < 2; ++rf)
#pragma unroll
                for (int cf = 0; cf < 4; ++cf)
#pragma unroll
                    for (int r = 0; r < 4; ++r)
                        vt[((w - 2) * 32 + rf * 16 + ((l >> 4) << 2) + r) * 72 + cf * 16 + (l & 15)] = f2bf(acc[rf][cf][r]);
        }
        __syncthreads();                            // kt/vt visible; bufA prefetch drained (hidden)
        // KV += phi_k * v^T : wave w -> KV rows w*16..+15, all 64 cols
        __builtin_amdgcn_s_setprio(1);
#pragma unroll
        for (int kk = 0; kk < 2; ++kk) {
            bf16x8 a = *(const bf16x8*)(kt + (w * 16 + (l & 15)) * 72 + kk * 32 + (l >> 4) * 8);
#pragma unroll
            for (int cf = 0; cf < 4; ++cf) {
                bf16x8 bb = *(const bf16x8*)(vt + (cf * 16 + (l & 15)) * 72 + kk * 32 + (l >> 4) * 8);
                kvacc[cf] = __builtin_amdgcn_mfma_f32_16x16x32_bf16(a, bb, kvacc[cf], 0, 0, 0);
            }
        }
        __builtin_amdgcn_s_setprio(0);
        // no trailing barrier: next kt/vt write is after next mid-loop barrier
    }

    float* kvp = (float*)(ws + KVP_OFF) + ((size_t)(bh * 4 + s)) * 4096;
#pragma unroll
    for (int cf = 0; cf < 4; ++cf)
#pragma unroll
        for (int r = 0; r < 4; ++r) {
            int c = w * 16 + ((l >> 4) << 2) + r;
            kvp[c * 64 + cf * 16 + (l & 15)] = kvacc[cf][r];
        }
    if (w < 2) {
        float* ksp = (float*)(ws + KSP_OFF) + (bh * 4 + s) * 64;
#pragma unroll
        for (int rf = 0; rf < 2; ++rf)
#pragma unroll
            for (int r = 0; r < 4; ++r) {
                float v = ksum[rf][r];
                v += __shfl_xor(v, 1); v += __shfl_xor(v, 2);
                v += __shfl_xor(v, 4); v += __shfl_xor(v, 8);
                if ((l & 15) == 0)
                    ksp[w * 32 + rf * 16 + ((l >> 4) << 2) + r] = v;
            }
    }
}

// per (b,h,chunk): in-block reduce KV partials -> aext, recompute phi(q) from xT,
// out = (A_ext*phi_q)/denom; dbuf prefetch. T5 setprio around MFMA clusters.
__global__ __launch_bounds__(256) void k_out4(const char* __restrict__ ws, float* __restrict__ out) {
    __shared__ unsigned short bufA[64 * 128];  // 16 KB
    __shared__ unsigned short bufB[64 * 128];  // 16 KB
    __shared__ unsigned short qt[64 * 64];     // [m][c] swizzled, 8 KB
    __shared__ unsigned short aext[80 * 72];   // 11.25 KB
    int t = threadIdx.x, l = t & 63, w = t >> 6;
    int blk = blockIdx.x;
    int wid = ((blk & 7) << 6) | (blk >> 3);   // XCD-chunked swizzle (512 = 8*64)
    int chunk = wid & 3, bh = wid >> 2;
    int b = bh >> 3, h = bh & 7;

    // in-block reduce of the 4 KV/ksum partials -> aext (replaces k_reduce)
    {
        const float* kvp = (const float*)(ws + KVP_OFF) + (size_t)bh * 4 * 4096;
        const float* ksp = (const float*)(ws + KSP_OFF) + bh * 4 * 64;
        for (int j = t; j < 4096; j += 256) {
            float v = kvp[j] + kvp[4096 + j] + kvp[8192 + j] + kvp[12288 + j];
            aext[(j & 63) * 72 + (j >> 6)] = f2bf(v);   // A_ext[d][c] = KV[c][d]
        }
        if (t < 64) {
            float v = ksp[t] + ksp[64 + t] + ksp[128 + t] + ksp[192 + t];
            aext[64 * 72 + t] = f2bf(v);
        }
        for (int j = t; j < 15 * 64; j += 256)
            aext[(65 + (j >> 6)) * 72 + (j & 63)] = 0;
    }

    const unsigned short* xtb = (const unsigned short*)(ws + XT_OFF) + (size_t)b * MM * CIN;
    const unsigned short* wq = (const unsigned short*)(ws + WQ_OFF);
    // wave w: q rows (w>>1)*32 + rf*16, m cols (w&1)*32 + mf*16
    bf16x8 wreg[2][8];
#pragma unroll
    for (int rf = 0; rf < 2; ++rf)
#pragma unroll
        for (int kk = 0; kk < 8; ++kk)
            wreg[rf][kk] = *(const bf16x8*)(wq + (size_t)(h * 64 + (w >> 1) * 32 + rf * 16 + (l & 15)) * CIN + kk * 32 + (l >> 4) * 8);

    const float* pe = (h < 4) ? (const float*)(ws + PEH_OFF) : (const float*)(ws + PEW_OFF);
    int obase = h * 64 - (h < 4 ? 0 : 256);
    float* outbh = out + ((size_t)(b * COUT + h * DH)) * MM;

    const unsigned short* tile0 = xtb + (size_t)(chunk * 1024) * CIN;
    stage_half(tile0, 0, bufA, l, w);
    __syncthreads();                            // also covers aext writes

    for (int ms = 0; ms < 16; ++ms) {
        int m0 = chunk * 1024 + ms * 64;
        const unsigned short* tilep = xtb + (size_t)m0 * CIN;
        stage_half(tilep, 1, bufB, l, w);          // prefetch half1

        f32x4 acc[2][2] = {};
        __builtin_amdgcn_s_setprio(1);
#pragma unroll
        for (int kk = 0; kk < 4; ++kk) {           // qGEMM half0
            bf16x8 bfr[2];
#pragma unroll
            for (int mf = 0; mf < 2; ++mf)
                bfr[mf] = ldsBh(bufA, (w & 1) * 32 + mf * 16 + (l & 15), kk * 32 + (l >> 4) * 8);
#pragma unroll
            for (int rf = 0; rf < 2; ++rf)
#pragma unroll
                for (int mf = 0; mf < 2; ++mf)
                    acc[rf][mf] = __builtin_amdgcn_mfma_f32_16x16x32_bf16(wreg[rf][kk], bfr[mf], acc[rf][mf], 0, 0, 0);
        }
        __builtin_amdgcn_s_setprio(0);
        __syncthreads();                            // bufB ready; PV(ms-1) qt-reads separated

        if (ms < 15)
            stage_half(tilep + 64 * CIN, 0, bufA, l, w);   // prefetch next half0
        __builtin_amdgcn_s_setprio(1);
#pragma unroll
        for (int kk = 0; kk < 4; ++kk) {           // qGEMM half1
            bf16x8 bfr[2];
#pragma unroll
            for (int mf = 0; mf < 2; ++mf)
                bfr[mf] = ldsBh(bufB, (w & 1) * 32 + mf * 16 + (l & 15), kk * 32 + (l >> 4) * 8);
#pragma unroll
            for (int rf = 0; rf < 2; ++rf)
#pragma unroll
                for (int mf = 0; mf < 2; ++mf)
                    acc[rf][mf] = __builtin_amdgcn_mfma_f32_16x16x32_bf16(wreg[rf][4 + kk], bfr[mf], acc[rf][mf], 0, 0, 0);
        }
        __builtin_amdgcn_s_setprio(0);
        int im = m0 >> 6;
#pragma unroll
        for (int rf = 0; rf < 2; ++rf) {
#pragma unroll
            for (int mf = 0; mf < 2; ++mf) {
                int mloc = (w & 1) * 32 + mf * 16 + (l & 15);
#pragma unroll
                for (int r = 0; r < 4; ++r) {
                    int c = (w >> 1) * 32 + rf * 16 + ((l >> 4) << 2) + r;
                    int o = obase + c;
                    float pev = (h < 4) ? pe[o * 64 + im] : pe[o * 64 + mloc];
                    float v = phi_elu(acc[rf][mf][r] + pev);
                    unsigned off = (unsigned)(mloc * 128) + (((unsigned)(c * 2)) ^ ((unsigned)(mloc & 7) << 4));
                    *(unsigned short*)((char*)qt + off) = f2bf(v);
                }
            }
        }
        __syncthreads();                            // qt visible; bufA prefetch drained (hidden)

        // PV: wave w owns m-cols w*16..+15
        f32x4 acc2[5] = {};
        __builtin_amdgcn_s_setprio(1);
#pragma unroll
        for (int kk = 0; kk < 2; ++kk) {
            int m = w * 16 + (l & 15);
            unsigned koff = (unsigned)(kk * 64 + (l >> 4) * 16);
            unsigned off = (unsigned)(m * 128) + (koff ^ ((unsigned)(m & 7) << 4));
            bf16x8 bb = *(const bf16x8*)((const char*)qt + off);
#pragma unroll
            for (int rf = 0; rf < 5; ++rf) {
                bf16x8 a = *(const bf16x8*)(aext + (rf * 16 + (l & 15)) * 72 + kk * 32 + (l >> 4) * 8);
                acc2[rf] = __builtin_amdgcn_mfma_f32_16x16x32_bf16(a, bb, acc2[rf], 0, 0, 0);
            }
        }
        __builtin_amdgcn_s_setprio(0);
        float den = __shfl(acc2[4][0], l & 15);
        float inv = 1.f / fmaxf(den, 1e-6f);
        int mcol = m0 + w * 16 + (l & 15);
#pragma unroll
        for (int rf = 0; rf < 4; ++rf)
#pragma unroll
            for (int r = 0; r < 4; ++r)
                outbh[(size_t)(rf * 16 + ((l >> 4) << 2) + r) * MM + mcol] = acc2[rf][r] * inv;
        // no trailing barrier: next qt write is after next mid-loop barrier
    }
}

// ================= OLD (fallback) PATH =================

__global__ void k_prep(const float* __restrict__ Wq, const float* __restrict__ Wk,
                       const float* __restrict__ Wv, char* __restrict__ ws) {
    int idx = blockIdx.x * 256 + threadIdx.x;
    if (idx < 32768) {
        int which = idx >> 14;
        int r = idx & 16383;
        int c = r >> 6, pos = r & 63;
        float div = __expf(-logf(10000.f) * (float)(c >> 1) * (1.f / 128.f));
        float t = (float)pos * div;
        float v = (c & 1) ? cosf(t) : sinf(t);
        ((float*)(ws + (which ? PEW_OFF : PEH_OFF)))[r] = v;
        return;
    }
    idx -= 32768;
    if (idx < COUT * CIN) {
        ((unsigned short*)(ws + WQ_OFF))[idx] = f2bf(Wq[idx]);
        return;
    }
    idx -= COUT * CIN;
    if (idx < NH * 128 * CIN) {
        int h = idx >> 15;
        int r = idx & 32767;
        int row = r >> 8, c = r & 255;
        float v = (row < 64) ? Wk[(h * 64 + row) * CIN + c]
                             : Wv[(h * 64 + row - 64) * CIN + c];
        ((unsigned short*)(ws + WKV_OFF))[idx] = f2bf(v);
    }
}

template<int NTHR>
__device__ __forceinline__ void stage_xT(const float* __restrict__ xb, int m0,
                                         unsigned short* __restrict__ lds, int t) {
    int mg = t & 15;
    for (int c = (t >> 4); c < CIN; c += NTHR / 16) {
        const float* src = xb + c * MM + m0 + mg;
#pragma unroll
        for (int j = 0; j < 4; ++j) {
            int m = mg + 16 * j;
            unsigned off = (unsigned)(m * 512) + (((unsigned)(c * 2)) ^ ((unsigned)(m & 7) << 4));
            *(unsigned short*)((char*)lds + off) = f2bf(src[16 * j]);
        }
    }
}
__device__ __forceinline__ bf16x8 ldsB(const unsigned short* lds, int n, int k) {
    unsigned off = (unsigned)(n * 512) + (((unsigned)(k * 2)) ^ ((unsigned)(n & 7) << 4));
    return *(const bf16x8*)((const char*)lds + off);
}

__global__ __launch_bounds__(512) void k_qgemm(const float* __restrict__ x,
                                               const char* __restrict__ ws,
                                               float* __restrict__ out) {
    __shared__ unsigned short xT[64 * 256];
    int t = threadIdx.x, l = t & 63, w = t >> 6;
    int gx = blockIdx.x;
    int rt = gx & 1;
    int ct = gx >> 1;
    int b = ct >> 6;
    int m0 = (ct & 63) * 64;
    const float* xb = x + (size_t)b * CIN * MM;

    const unsigned short* wq = (const unsigned short*)(ws + WQ_OFF);
    int r0 = rt * 256 + w * 32;
    bf16x8 wreg[2][8];
#pragma unroll
    for (int rf = 0; rf < 2; ++rf)
#pragma unroll
        for (int kk = 0; kk < 8; ++kk)
            wreg[rf][kk] = *(const bf16x8*)(wq + (size_t)(r0 + rf * 16 + (l & 15)) * CIN + kk * 32 + (l >> 4) * 8);

    stage_xT<512>(xb, m0, xT, t);
    __syncthreads();

    f32x4 acc[2][4] = {};
#pragma unroll
    for (int kk = 0; kk < 8; ++kk) {
        bf16x8 bfr[4];
#pragma unroll
        for (int cf = 0; cf < 4; ++cf)
            bfr[cf] = ldsB(xT, cf * 16 + (l & 15), kk * 32 + (l >> 4) * 8);
#pragma unroll
        for (int rf = 0; rf < 2; ++rf)
#pragma unroll
            for (int cf = 0; cf < 4; ++cf)
                acc[rf][cf] = __builtin_amdgcn_mfma_f32_16x16x32_bf16(wreg[rf][kk], bfr[cf], acc[rf][cf], 0, 0, 0);
    }

    const float* peh = (const float*)(ws + PEH_OFF);
    const float* pew = (const float*)(ws + PEW_OFF);
    int im = m0 >> 6;
#pragma unroll
    for (int rf = 0; rf < 2; ++rf) {
#pragma unroll
        for (int cf = 0; cf < 4; ++cf) {
            int mloc = cf * 16 + (l & 15);
#pragma unroll
            for (int r = 0; r < 4; ++r) {
                int o = r0 + rf * 16 + ((l >> 4) << 2) + r;
                float pe = (rt == 0) ? peh[o * 64 + im] : pew[(o - 256) * 64 + mloc];
                float v = phi_elu(acc[rf][cf][r] + pe);
                out[((size_t)(b * COUT + o)) * MM + m0 + mloc] = v;
            }
        }
    }
}

__global__ __launch_bounds__(256) void k_kv(const float* __restrict__ x,
                                            char* __restrict__ ws) {
    __shared__ unsigned short xT[64 * 256];
    __shared__ unsigned short kt[64 * 72];
    __shared__ unsigned short vt[64 * 72];
    int t = threadIdx.x, l = t & 63, w = t >> 6;
    int blk = blockIdx.x;
    int s = blk & 3;
    int bh = blk >> 2;
    int b = bh >> 3, h = bh & 7;
    const float* xb = x + (size_t)b * CIN * MM;

    const unsigned short* wkv = (const unsigned short*)(ws + WKV_OFF) + (size_t)h * 128 * CIN;
    bf16x8 wreg[2][8];
#pragma unroll
    for (int rf = 0; rf < 2; ++rf)
#pragma unroll
        for (int kk = 0; kk < 8; ++kk)
            wreg[rf][kk] = *(const bf16x8*)(wkv + (size_t)(w * 32 + rf * 16 + (l & 15)) * CIN + kk * 32 + (l >> 4) * 8);

    f32x4 kvacc[4] = {};
    float ksum[2][4] = {};

    for (int ms = 0; ms < 16; ++ms) {
        int m0 = s * 1024 + ms * 64;
        if (ms) __syncthreads();
        stage_xT<256>(xb, m0, xT, t);
        __syncthreads();

        f32x4 acc[2][4] = {};
#pragma unroll
        for (int kk = 0; kk < 8; ++kk) {
            bf16x8 bfr[4];
#pragma unroll
            for (int cf = 0; cf < 4; ++cf)
                bfr[cf] = ldsB(xT, cf * 16 + (l & 15), kk * 32 + (l >> 4) * 8);
#pragma unroll
            for (int rf = 0; rf < 2; ++rf)
#pragma unroll
                for (int cf = 0; cf < 4; ++cf)
                    acc[rf][cf] = __builtin_amdgcn_mfma_f32_16x16x32_bf16(wreg[rf][kk], bfr[cf], acc[rf][cf], 0, 0, 0);
        }

        if (w < 2) {
#pragma unroll
            for (int rf = 0; rf < 2; ++rf)
#pragma unroll
                for (int cf = 0; cf < 4; ++cf)
#pragma unroll
                    for (int r = 0; r < 4; ++r) {
                        float p = phi_elu(acc[rf][cf][r]);
                        ksum[rf][r] += p;
                        kt[(w * 32 + rf * 16 + ((l >> 4) << 2) + r) * 72 + cf * 16 + (l & 15)] = f2bf(p);
                    }
        } else {
#pragma unroll
            for (int rf = 0; rf < 2; ++rf)
#pragma unroll
                for (int cf = 0; cf < 4; ++cf)
#pragma unroll
                    for (int r = 0; r < 4; ++r)
                        vt[((w - 2) * 32 + rf * 16 + ((l >> 4) << 2) + r) * 72 + cf * 16 + (l & 15)] = f2bf(acc[rf][cf][r]);
        }
        __syncthreads();

#pragma unroll
        for (int kk = 0; kk < 2; ++kk) {
            bf16x8 a = *(const bf16x8*)(kt + (w * 16 + (l & 15)) * 72 + kk * 32 + (l >> 4) * 8);
#pragma unroll
            for (int cf = 0; cf < 4; ++cf) {
                bf16x8 bb = *(const bf16x8*)(vt + (cf * 16 + (l & 15)) * 72 + kk * 32 + (l >> 4) * 8);
                kvacc[cf] = __builtin_amdgcn_mfma_f32_16x16x32_bf16(a, bb, kvacc[cf], 0, 0, 0);
            }
        }
    }

    float* kvp = (float*)(ws + KVP_OFF) + ((size_t)(bh * 4 + s)) * 4096;
#pragma unroll
    for (int cf = 0; cf < 4; ++cf)
#pragma unroll
        for (int r = 0; r < 4; ++r) {
            int c = w * 16 + ((l >> 4) << 2) + r;
            kvp[c * 64 + cf * 16 + (l & 15)] = kvacc[cf][r];
        }
    if (w < 2) {
        float* ksp = (float*)(ws + KSP_OFF) + (bh * 4 + s) * 64;
#pragma unroll
        for (int rf = 0; rf < 2; ++rf)
#pragma unroll
            for (int r = 0; r < 4; ++r) {
                float v = ksum[rf][r];
                v += __shfl_xor(v, 1); v += __shfl_xor(v, 2);
                v += __shfl_xor(v, 4); v += __shfl_xor(v, 8);
                if ((l & 15) == 0)
                    ksp[w * 32 + rf * 16 + ((l >> 4) << 2) + r] = v;
            }
    }
}

__global__ void k_reduce(char* __restrict__ ws) {
    int bh = blockIdx.x;
    const float* kvp = (const float*)(ws + KVP_OFF) + (size_t)bh * 4 * 4096;
    const float* ksp = (const float*)(ws + KSP_OFF) + bh * 4 * 64;
    unsigned short* a = (unsigned short*)(ws + AEXT_OFF) + (size_t)bh * 80 * 64;
    for (int i = threadIdx.x; i < 80 * 64; i += 256) {
        int d = i >> 6, c = i & 63;
        float v = 0.f;
        if (d < 64) {
#pragma unroll
            for (int s = 0; s < 4; ++s) v += kvp[s * 4096 + c * 64 + d];
        } else if (d == 64) {
#pragma unroll
            for (int s = 0; s < 4; ++s) v += ksp[s * 64 + c];
        }
        a[i] = f2bf(v);
    }
}

__global__ __launch_bounds__(256) void k_out(const char* __restrict__ ws,
                                             float* __restrict__ out) {
    __shared__ unsigned short aext[80 * 72];
    __shared__ unsigned short qt[64 * 72];
    int t = threadIdx.x, l = t & 63, w = t >> 6;
    int blk = blockIdx.x;
    int chunk = blk & 7, bh = blk >> 3;
    int b = bh >> 3, h = bh & 7;

    const unsigned short* asrc = (const unsigned short*)(ws + AEXT_OFF) + (size_t)bh * 80 * 64;
    for (int i = t; i < 80 * 8; i += 256) {
        int row = i >> 3, ch = i & 7;
        *(bf16x8*)(aext + row * 72 + ch * 8) = *(const bf16x8*)(asrc + row * 64 + ch * 8);
    }
    float* outbh = out + ((size_t)(b * COUT + h * DH)) * MM;

    for (int ms = 0; ms < 8; ++ms) {
        int m0 = chunk * 512 + ms * 64;
        __syncthreads();
        {
            int mg = t & 15;
            for (int c = t >> 4; c < 64; c += 16) {
                const float* src = outbh + (size_t)c * MM + m0 + mg;
#pragma unroll
                for (int j = 0; j < 4; ++j)
                    qt[(mg + 16 * j) * 72 + c] = f2bf(src[16 * j]);
            }
        }
        __syncthreads();
        f32x4 acc[5] = {};
#pragma unroll
        for (int kk = 0; kk < 2; ++kk) {
            bf16x8 bb = *(const bf16x8*)(qt + (w * 16 + (l & 15)) * 72 + kk * 32 + (l >> 4) * 8);
#pragma unroll
            for (int rf = 0; rf < 5; ++rf) {
                bf16x8 a = *(const bf16x8*)(aext + (rf * 16 + (l & 15)) * 72 + kk * 32 + (l >> 4) * 8);
                acc[rf] = __builtin_amdgcn_mfma_f32_16x16x32_bf16(a, bb, acc[rf], 0, 0, 0);
            }
        }
        float den = __shfl(acc[4][0], l & 15);
        float inv = 1.f / fmaxf(den, 1e-6f);
        int mcol = m0 + w * 16 + (l & 15);
#pragma unroll
        for (int rf = 0; rf < 4; ++rf)
#pragma unroll
            for (int r = 0; r < 4; ++r)
                outbh[(size_t)(rf * 16 + ((l >> 4) << 2) + r) * MM + mcol] = acc[rf][r] * inv;
    }
}

extern "C" void kernel_launch(void* const* d_in, const int* in_sizes, int n_in,
                              void* d_out, int out_size, void* d_ws, size_t ws_size,
                              hipStream_t stream) {
    const float* x  = (const float*)d_in[0];
    const float* Wq = (const float*)d_in[1];
    const float* Wk = (const float*)d_in[2];
    const float* Wv = (const float*)d_in[3];
    float* out = (float*)d_out;
    char* ws = (char*)d_ws;

    if (ws_size >= WS_NEED) {
        hipLaunchKernelGGL(k_init, dim3(5760), dim3(256), 0, stream, x, Wq, Wk, Wv, ws);
        hipLaunchKernelGGL(k_kv4,  dim3(512),  dim3(256), 0, stream, ws);
        hipLaunchKernelGGL(k_out4, dim3(512),  dim3(256), 0, stream, ws, out);
    } else {
        hipLaunchKernelGGL(k_prep,   dim3(1664), dim3(256), 0, stream, Wq, Wk, Wv, ws);
        hipLaunchKernelGGL(k_qgemm,  dim3(2048), dim3(512), 0, stream, x, ws, out);
        hipLaunchKernelGGL(k_kv,     dim3(512),  dim3(256), 0, stream, x, ws);
        hipLaunchKernelGGL(k_reduce, dim3(128),  dim3(256), 0, stream, ws);
        hipLaunchKernelGGL(k_out,    dim3(1024), dim3(256), 0, stream, ws, out);
    }
}